// Round 8
// baseline (301.701 us; speedup 1.0000x reference)
//
#include <hip/hip_runtime.h>
#include <cstdint>
#include <cstddef>

// ---------------- problem constants (from setup_inputs) ----------------
constexpr int Nn   = 50000;            // nodes
constexpr int Ee   = 800000;           // edges (without self loops)
constexpr int ETot = Ee + Nn;          // 850000 with self loops
constexpr int H1   = 8;                // heads layer 1
constexpr int C1h  = 32;               // channels/head layer 1
constexpr int HC1  = 256;              // H1*C1h
constexpr int C2   = 40;               // classes (layer 2, 1 head)
constexpr int S2   = 64;               // padded h2 row stride (shorts) = 128 B
constexpr float SLOPE = 0.2f;          // leaky_relu negative slope
constexpr int NB_SCAN = (Nn + 255) / 256;   // 196 scan blocks

typedef __attribute__((ext_vector_type(8))) short bf16x8;   // 8 bf16 (4 VGPRs)
typedef __attribute__((ext_vector_type(4))) float f32x4;    // MFMA accumulator

__device__ __forceinline__ ushort f2bf(float f) {           // RNE f32->bf16
    uint u = __float_as_uint(f);
    u += 0x7fffu + ((u >> 16) & 1u);
    return (ushort)(u >> 16);
}
__device__ __forceinline__ float bf2f(ushort b) {
    return __uint_as_float(((uint)b) << 16);
}

// async global->LDS, 16 B per lane; LDS dest must be wave-uniform base + lane*16
__device__ __forceinline__ void gload16(const void* g, void* lds) {
    typedef const __attribute__((address_space(1))) unsigned int GU;
    typedef __attribute__((address_space(3))) unsigned int LU;
    __builtin_amdgcn_global_load_lds((GU*)g, (LU*)lds, 16, 0, 0);
}

// ====== merged prep: x split (bf16 hi/lo) | W1 pack | W2 pack | dst hist =====
// W1 -> WT2[((k'/8)*256 + col)*8 + k'%8], k' in [0,768): [Whi; Whi; Wlo]
// W2 -> WT2b[((k'/8)*48 + col)*8 + k'%8], cols 40..47 zero-padded
__global__ void k_prep(const float* __restrict__ x, ushort* __restrict__ xhi,
                       ushort* __restrict__ xlo, const float* __restrict__ w1,
                       ushort* __restrict__ WT2, const float* __restrict__ w2,
                       ushort* __restrict__ WT2b, const int* __restrict__ dstA,
                       int* __restrict__ counts) {
    int t = blockIdx.x * blockDim.x + threadIdx.x;
    constexpr int n4 = Nn * HC1 / 4;                  // 3.2M
    if (t < n4) {
        float4 v = *(const float4*)(x + (size_t)t * 4);
        ushort4 h, l;
        h.x = f2bf(v.x); l.x = f2bf(v.x - bf2f(h.x));
        h.y = f2bf(v.y); l.y = f2bf(v.y - bf2f(h.y));
        h.z = f2bf(v.z); l.z = f2bf(v.z - bf2f(h.z));
        h.w = f2bf(v.w); l.w = f2bf(v.w - bf2f(h.w));
        *(ushort4*)(xhi + (size_t)t * 4) = h;
        *(ushort4*)(xlo + (size_t)t * 4) = l;
    }
    if (t < ETot) {
        int d = (t < Ee) ? dstA[t] : t - Ee;
        atomicAdd(&counts[d], 1);
    }
    if (t < 256 * 256) {
        int k = t >> 8, col = t & 255;
        float w = w1[(size_t)k * 256 + col];
        ushort h = f2bf(w), l = f2bf(w - bf2f(h));
        int kb = k >> 3, kr = k & 7;
        WT2[((size_t)(kb)      * 256 + col) * 8 + kr] = h;
        WT2[((size_t)(kb + 32) * 256 + col) * 8 + kr] = h;
        WT2[((size_t)(kb + 64) * 256 + col) * 8 + kr] = l;
    }
    if (t < 256 * 48) {
        int k = t / 48, col = t % 48;
        float w = (col < C2) ? w2[(size_t)k * C2 + col] : 0.f;
        ushort h = f2bf(w), l = f2bf(w - bf2f(h));
        int kb = k >> 3, kr = k & 7;
        WT2b[((size_t)(kb)      * 48 + col) * 8 + kr] = h;
        WT2b[((size_t)(kb + 32) * 48 + col) * 8 + kr] = h;
        WT2b[((size_t)(kb + 64) * 48 + col) * 8 + kr] = l;
    }
}

// ================= CSR build (scan -> scatter) =================
__global__ __launch_bounds__(256) void k_scan_block(const int* __restrict__ counts,
                                                    int* __restrict__ exsc,
                                                    int* __restrict__ bsum) {
    __shared__ int sm[256];
    int i = blockIdx.x * 256 + threadIdx.x;
    int v = (i < Nn) ? counts[i] : 0;
    sm[threadIdx.x] = v;
    __syncthreads();
#pragma unroll
    for (int off = 1; off < 256; off <<= 1) {
        int t = (threadIdx.x >= off) ? sm[threadIdx.x - off] : 0;
        __syncthreads();
        sm[threadIdx.x] += t;
        __syncthreads();
    }
    if (i < Nn) exsc[i] = sm[threadIdx.x] - v;
    if (threadIdx.x == 255) bsum[blockIdx.x] = sm[255];
}

__global__ __launch_bounds__(256) void k_scan_top(const int* __restrict__ bsum,
                                                  int* __restrict__ boff) {
    __shared__ int sm[256];
    int t = threadIdx.x;
    int v = (t < NB_SCAN) ? bsum[t] : 0;
    sm[t] = v;
    __syncthreads();
#pragma unroll
    for (int off = 1; off < 256; off <<= 1) {
        int x = (t >= off) ? sm[t - off] : 0;
        __syncthreads();
        sm[t] += x;
        __syncthreads();
    }
    if (t < NB_SCAN) boff[t] = sm[t] - v;
}

__global__ void k_finalize_off(const int* __restrict__ exsc, const int* __restrict__ boff,
                               int* __restrict__ row_off, int* __restrict__ cursor) {
    int i = blockIdx.x * blockDim.x + threadIdx.x;
    if (i < Nn) {
        int r = exsc[i] + boff[i >> 8];
        row_off[i] = r;
        cursor[i] = r;
    }
    if (i == 0) row_off[Nn] = ETot;
}

__global__ void k_scatter(const int* __restrict__ srcA, const int* __restrict__ dstA,
                          int* __restrict__ cursor, int* __restrict__ csr_src) {
    int e = blockIdx.x * blockDim.x + threadIdx.x;
    if (e >= ETot) return;
    int s, d;
    if (e < Ee) { s = srcA[e]; d = dstA[e]; } else { s = e - Ee; d = s; }
    int pos = atomicAdd(&cursor[d], 1);
    csr_src[pos] = s;
}

// ========== GEMM1 (MFMA bf16, split precision): [M,768']x[768',256] ==========
// 128x128 tile, BK=32, 4 waves (64x64 each). global_load_lds direct staging,
// LDS double-buffer, ONE barrier per K-step.
__global__ __launch_bounds__(256, 4) void k_gemm1_mfma(const ushort* __restrict__ xhi,
                                                       const ushort* __restrict__ xlo,
                                                       const ushort* __restrict__ WT2,
                                                       ushort* __restrict__ h1b, int M) {
    constexpr int BK = 32, KD = 768;
    __shared__ __align__(16) ushort As[2][128 * BK];   // 8 KB each: (kc*128+row)*8
    __shared__ __align__(16) ushort Bs[2][128 * BK];
    const int tid = threadIdx.x;
    const int bm = blockIdx.x * 128, bn = blockIdx.y * 128;
    const int lane = tid & 63;
    const int wid = tid >> 6;
    const int wm = wid >> 1, wn = wid & 1;
    const int l16 = lane & 15, lk = lane >> 4;

    // staging: chunk q in {0,1}: idx = q*256 + tid; kc = idx>>7, row/col = idx&127
    const int srow = tid & 127, skc = tid >> 7;
    int arow = bm + srow; arow = arow < M ? arow : M - 1;

    auto stage = [&](int buf, int k0) {
        const ushort* xsec; int ks;
        if (k0 < 256)      { xsec = xhi; ks = k0; }
        else if (k0 < 512) { xsec = xlo; ks = k0 - 256; }
        else               { xsec = xhi; ks = k0 - 512; }
        const ushort* a_base = xsec + (size_t)arow * 256 + ks;
        gload16(a_base + skc * 8,        As[buf] + tid * 8);
        gload16(a_base + (skc + 2) * 8,  As[buf] + (256 + tid) * 8);
        const ushort* b_base = WT2 + ((size_t)((k0 >> 3) + skc) * 256 + bn + srow) * 8;
        gload16(b_base,                  Bs[buf] + tid * 8);
        gload16(b_base + 2 * 256 * 8,    Bs[buf] + (256 + tid) * 8);
    };

    f32x4 acc[4][4] = {};
    stage(0, 0);
    __syncthreads();                          // drains vmcnt(0) + barrier
    int buf = 0;
    for (int k0 = 0; k0 < KD; k0 += BK) {
        if (k0 + BK < KD) stage(buf ^ 1, k0 + BK);
        bf16x8 a[4], b[4];
#pragma unroll
        for (int m = 0; m < 4; m++)
            a[m] = *(const bf16x8*)(As[buf] + (lk * 128 + wm * 64 + m * 16 + l16) * 8);
#pragma unroll
        for (int n = 0; n < 4; n++)
            b[n] = *(const bf16x8*)(Bs[buf] + (lk * 128 + wn * 64 + n * 16 + l16) * 8);
#pragma unroll
        for (int m = 0; m < 4; m++)
#pragma unroll
            for (int n = 0; n < 4; n++)
                acc[m][n] = __builtin_amdgcn_mfma_f32_16x16x32_bf16(a[m], b[n], acc[m][n], 0, 0, 0);
        __syncthreads();                      // drains this iter's stage too
        buf ^= 1;
    }
#pragma unroll
    for (int m = 0; m < 4; m++) {
#pragma unroll
        for (int j = 0; j < 4; j++) {
            int row = bm + wm * 64 + m * 16 + lk * 4 + j;
            if (row < M) {
#pragma unroll
                for (int n = 0; n < 4; n++)
                    h1b[(size_t)row * 256 + bn + wn * 64 + n * 16 + l16] = f2bf(acc[m][n][j]);
            }
        }
    }
}

// ========== GEMM2 (MFMA bf16, split precision): [M,768']x[768',48] ==========
// 128-row tile, 4 waves x 32 rows (acc[2][3]); output rows padded to stride 64.
__global__ __launch_bounds__(256, 4) void k_gemm2_mfma(const ushort* __restrict__ hi,
                                                       const ushort* __restrict__ lo,
                                                       const ushort* __restrict__ WT,
                                                       ushort* __restrict__ h2, int M) {
    constexpr int BK = 32, KD = 768;
    __shared__ __align__(16) ushort As[2][128 * BK];   // (kc*128+row)*8
    __shared__ __align__(16) ushort Bs[2][48 * BK];    // idx*8, idx = kc*48+col
    const int tid = threadIdx.x;
    const int bm = blockIdx.x * 128;
    const int lane = tid & 63;
    const int w = tid >> 6;
    const int l16 = lane & 15, lk = lane >> 4;

    const int srow = tid & 127, skc = tid >> 7;
    int arow = bm + srow; arow = arow < M ? arow : M - 1;

    auto stage = [&](int buf, int k0) {
        const ushort* xsec; int ks;
        if (k0 < 256)      { xsec = hi; ks = k0; }
        else if (k0 < 512) { xsec = lo; ks = k0 - 256; }
        else               { xsec = hi; ks = k0 - 512; }
        const ushort* a_base = xsec + (size_t)arow * 256 + ks;
        gload16(a_base + skc * 8,       As[buf] + tid * 8);
        gload16(a_base + (skc + 2) * 8, As[buf] + (256 + tid) * 8);
        if (tid < 192)   // B tile is a linear 3 KB copy (packed layout)
            gload16(WT + ((size_t)(k0 >> 3) * 48 + tid) * 8, Bs[buf] + tid * 8);
    };

    f32x4 acc[2][3] = {};
    stage(0, 0);
    __syncthreads();
    int buf = 0;
    for (int k0 = 0; k0 < KD; k0 += BK) {
        if (k0 + BK < KD) stage(buf ^ 1, k0 + BK);
        bf16x8 a2[2], b2[3];
#pragma unroll
        for (int m = 0; m < 2; m++)
            a2[m] = *(const bf16x8*)(As[buf] + (lk * 128 + w * 32 + m * 16 + l16) * 8);
#pragma unroll
        for (int n = 0; n < 3; n++)
            b2[n] = *(const bf16x8*)(Bs[buf] + (lk * 48 + n * 16 + l16) * 8);
#pragma unroll
        for (int m = 0; m < 2; m++)
#pragma unroll
            for (int n = 0; n < 3; n++)
                acc[m][n] = __builtin_amdgcn_mfma_f32_16x16x32_bf16(a2[m], b2[n], acc[m][n], 0, 0, 0);
        __syncthreads();
        buf ^= 1;
    }
#pragma unroll
    for (int m = 0; m < 2; m++)
#pragma unroll
        for (int n = 0; n < 3; n++)
#pragma unroll
            for (int j = 0; j < 4; j++) {
                int row = bm + w * 32 + m * 16 + lk * 4 + j;
                if (row < M)
                    h2[(size_t)row * S2 + n * 16 + l16] = f2bf(acc[m][n][j]);
            }
}

// ---------------- per-node attention coefficients (bf16 h) ----------------
template <int H, int C, int STRIDE>
__global__ void k_alpha_b(const ushort* __restrict__ h, const float* __restrict__ a_s,
                          const float* __restrict__ a_d, float* __restrict__ asrc,
                          float* __restrict__ adst, int N) {
    __shared__ float ls[H * C], ldd[H * C];
    for (int i = threadIdx.x; i < H * C; i += blockDim.x) { ls[i] = a_s[i]; ldd[i] = a_d[i]; }
    __syncthreads();
    int t = blockIdx.x * blockDim.x + threadIdx.x;
    if (t >= N * H) return;
    int n = t / H, hh = t % H;
    const ushort* row = h + (size_t)n * STRIDE + hh * C;
    float s = 0.f, dd = 0.f;
#pragma unroll
    for (int c = 0; c < C; c += 4) {
        ushort4 v = *(const ushort4*)(row + c);
        float f0 = bf2f(v.x), f1 = bf2f(v.y), f2 = bf2f(v.z), f3 = bf2f(v.w);
        s  += f0 * ls[hh * C + c] + f1 * ls[hh * C + c + 1] +
              f2 * ls[hh * C + c + 2] + f3 * ls[hh * C + c + 3];
        dd += f0 * ldd[hh * C + c] + f1 * ldd[hh * C + c + 1] +
              f2 * ldd[hh * C + c + 2] + f3 * ldd[hh * C + c + 3];
    }
    asrc[t] = s;
    adst[t] = dd;
}

// ======== layer-1 aggregation: half-wave per edge, 4-deep unrolled ========
__global__ __launch_bounds__(256) void k_gat_aggr1(const int* __restrict__ row_off,
                                                   const int* __restrict__ csr_src,
                                                   const float* __restrict__ asrc,
                                                   const float* __restrict__ adst,
                                                   const ushort* __restrict__ h1b,
                                                   const float* __restrict__ bias,
                                                   ushort* __restrict__ o_hi,
                                                   ushort* __restrict__ o_lo) {
    int wid = (blockIdx.x * 256 + threadIdx.x) >> 6;   // node id
    if (wid >= Nn) return;
    int lane = threadIdx.x & 63;
    int half = lane >> 5, l32 = lane & 31;
    int head = l32 >> 2;                 // 4 lanes per head, 8 ch each
    int c0 = l32 * 8;
    int beg = row_off[wid], end = row_off[wid + 1];
    float ad = adst[(size_t)wid * H1 + head];
    float acc[8] = {};
    float sump = 0.f;
    int i = beg + half;
    for (; i + 6 < end; i += 8) {        // 4 edges per half per iter
        int s0 = csr_src[i],     s1 = csr_src[i + 2];
        int s2 = csr_src[i + 4], s3 = csr_src[i + 6];
        float a0 = asrc[(size_t)s0 * H1 + head], a1 = asrc[(size_t)s1 * H1 + head];
        float a2 = asrc[(size_t)s2 * H1 + head], a3 = asrc[(size_t)s3 * H1 + head];
        bf16x8 v0 = *(const bf16x8*)(h1b + (size_t)s0 * HC1 + c0);
        bf16x8 v1 = *(const bf16x8*)(h1b + (size_t)s1 * HC1 + c0);
        bf16x8 v2 = *(const bf16x8*)(h1b + (size_t)s2 * HC1 + c0);
        bf16x8 v3 = *(const bf16x8*)(h1b + (size_t)s3 * HC1 + c0);
        float l0 = a0 + ad; l0 = l0 > 0.f ? l0 : SLOPE * l0;
        float l1 = a1 + ad; l1 = l1 > 0.f ? l1 : SLOPE * l1;
        float l2 = a2 + ad; l2 = l2 > 0.f ? l2 : SLOPE * l2;
        float l3 = a3 + ad; l3 = l3 > 0.f ? l3 : SLOPE * l3;
        float p0 = __expf(l0), p1 = __expf(l1), p2 = __expf(l2), p3 = __expf(l3);
        sump += (p0 + p1) + (p2 + p3);
#pragma unroll
        for (int j = 0; j < 8; j++)
            acc[j] += (p0 * bf2f((ushort)v0[j]) + p1 * bf2f((ushort)v1[j])) +
                      (p2 * bf2f((ushort)v2[j]) + p3 * bf2f((ushort)v3[j]));
    }
    for (; i < end; i += 2) {
        int s = csr_src[i];
        float a = asrc[(size_t)s * H1 + head];
        bf16x8 v = *(const bf16x8*)(h1b + (size_t)s * HC1 + c0);
        float l = a + ad; l = l > 0.f ? l : SLOPE * l;
        float p = __expf(l);
        sump += p;
#pragma unroll
        for (int j = 0; j < 8; j++) acc[j] += p * bf2f((ushort)v[j]);
    }
    // merge the two half-waves
    sump += __shfl_xor(sump, 32);
#pragma unroll
    for (int j = 0; j < 8; j++) acc[j] += __shfl_xor(acc[j], 32);
    if (half) return;
    float inv = 1.f / sump;              // degree >= 1 (self-loop)
    float4 b0 = *(const float4*)(bias + c0);
    float4 b1 = *(const float4*)(bias + c0 + 4);
    float bb[8] = {b0.x, b0.y, b0.z, b0.w, b1.x, b1.y, b1.z, b1.w};
    uint4 uh, ul;
    uint* uhp = (uint*)&uh; uint* ulp = (uint*)&ul;
#pragma unroll
    for (int q = 0; q < 4; q++) {
        float r0 = acc[2 * q] * inv + bb[2 * q];
        float r1 = acc[2 * q + 1] * inv + bb[2 * q + 1];
        r0 = r0 > 0.f ? r0 : __expf(r0) - 1.f;     // fused ELU
        r1 = r1 > 0.f ? r1 : __expf(r1) - 1.f;
        ushort h0 = f2bf(r0), h1v = f2bf(r1);
        ushort l0 = f2bf(r0 - bf2f(h0)), l1v = f2bf(r1 - bf2f(h1v));
        uhp[q] = (uint)h0 | ((uint)h1v << 16);
        ulp[q] = (uint)l0 | ((uint)l1v << 16);
    }
    *(uint4*)(o_hi + (size_t)wid * HC1 + c0) = uh;
    *(uint4*)(o_lo + (size_t)wid * HC1 + c0) = ul;
}

// ======== layer-2 aggregation: wave/node, lanes 0..39, padded bf16 h2 =======
__global__ __launch_bounds__(256) void k_gat_aggr2(const int* __restrict__ row_off,
                                                   const int* __restrict__ csr_src,
                                                   const float* __restrict__ asrc,
                                                   const float* __restrict__ adst,
                                                   const ushort* __restrict__ h2,
                                                   const float* __restrict__ bias,
                                                   float* __restrict__ out) {
    int wid = (blockIdx.x * 256 + threadIdx.x) >> 6;
    if (wid >= Nn) return;
    int lane = threadIdx.x & 63;
    int cl = lane < C2 ? lane : C2 - 1;            // clamp: lanes 40..63 read c39
    int beg = row_off[wid], end = row_off[wid + 1];
    float ad = adst[wid];
    float acc = 0.f, sump = 0.f;
    int i = beg;
    for (; i + 3 < end; i += 4) {
        int s0 = csr_src[i], s1 = csr_src[i + 1], s2 = csr_src[i + 2], s3 = csr_src[i + 3];
        float a0 = asrc[s0], a1 = asrc[s1], a2 = asrc[s2], a3 = asrc[s3];
        float v0 = bf2f(h2[(size_t)s0 * S2 + cl]);
        float v1 = bf2f(h2[(size_t)s1 * S2 + cl]);
        float v2 = bf2f(h2[(size_t)s2 * S2 + cl]);
        float v3 = bf2f(h2[(size_t)s3 * S2 + cl]);
        float l0 = a0 + ad; l0 = l0 > 0.f ? l0 : SLOPE * l0;
        float l1 = a1 + ad; l1 = l1 > 0.f ? l1 : SLOPE * l1;
        float l2 = a2 + ad; l2 = l2 > 0.f ? l2 : SLOPE * l2;
        float l3 = a3 + ad; l3 = l3 > 0.f ? l3 : SLOPE * l3;
        float p0 = __expf(l0), p1 = __expf(l1), p2 = __expf(l2), p3 = __expf(l3);
        sump += (p0 + p1) + (p2 + p3);
        acc += p0 * v0 + p1 * v1 + p2 * v2 + p3 * v3;
    }
    for (; i < end; i++) {
        int s = csr_src[i];
        float l = asrc[s] + ad;
        l = l > 0.f ? l : SLOPE * l;
        float pe = __expf(l);
        sump += pe;
        acc += pe * bf2f(h2[(size_t)s * S2 + cl]);
    }
    if (lane < C2) out[(size_t)wid * C2 + lane] = acc / sump + bias[lane];
}

// ---------------- launch ----------------
extern "C" void kernel_launch(void* const* d_in, const int* in_sizes, int n_in,
                              void* d_out, int out_size, void* d_ws, size_t ws_size,
                              hipStream_t stream) {
    const float* x   = (const float*)d_in[0];
    const int*   ei  = (const int*)d_in[1];
    const float* w1  = (const float*)d_in[2];
    const float* as1 = (const float*)d_in[3];
    const float* ad1 = (const float*)d_in[4];
    const float* b1  = (const float*)d_in[5];
    const float* w2  = (const float*)d_in[6];
    const float* as2 = (const float*)d_in[7];
    const float* ad2 = (const float*)d_in[8];
    const float* b2  = (const float*)d_in[9];
    float* outp = (float*)d_out;

    const int* srcA = ei;
    const int* dstA = ei + Ee;

    char* W = (char*)d_ws;
    size_t o = 0;
    auto allocB = [&](size_t bytes) { void* p = W + o; o += (bytes + 255) & ~(size_t)255; return p; };

    ushort* xhi   = (ushort*)allocB((size_t)Nn * HC1 * 2);   // 25.6 MB
    ushort* xlo   = (ushort*)allocB((size_t)Nn * HC1 * 2);   // 25.6 MB
    ushort* o1hi  = xhi;   // alias: out1 hi/lo reuse xhi/xlo after GEMM1
    ushort* o1lo  = xlo;
    ushort* wt2   = (ushort*)allocB((size_t)768 * 256 * 2);  // packed W1'
    ushort* wt2b  = (ushort*)allocB((size_t)768 * 48 * 2);   // packed W2'
    ushort* h1b   = (ushort*)allocB((size_t)Nn * HC1 * 2);   // 25.6 MB
    ushort* h2    = (ushort*)allocB((size_t)Nn * S2 * 2);    // 6.4 MB (padded)
    float*  asrc1 = (float*)allocB((size_t)Nn * H1 * 4);
    float*  adst1 = (float*)allocB((size_t)Nn * H1 * 4);
    float*  asrc2 = (float*)allocB((size_t)Nn * 4);
    float*  adst2 = (float*)allocB((size_t)Nn * 4);
    int* counts   = (int*)allocB((size_t)Nn * 4);
    int* exsc     = (int*)allocB((size_t)Nn * 4);
    int* bsum     = (int*)allocB(256 * 4);
    int* boff     = (int*)allocB(256 * 4);
    int* row_off  = (int*)allocB((size_t)(Nn + 1) * 4);
    int* cursor   = (int*)allocB((size_t)Nn * 4);
    int* csr_src  = (int*)allocB((size_t)ETot * 4);

    // ---- prep (split + weight packs + degree histogram, one dispatch) ----
    hipMemsetAsync(counts, 0, (size_t)Nn * sizeof(int), stream);
    k_prep<<<(Nn * HC1 / 4 + 255) / 256, 256, 0, stream>>>(
        x, xhi, xlo, w1, wt2, w2, wt2b, dstA, counts);

    // ---- CSR build (graph shared by both layers) ----
    k_scan_block<<<NB_SCAN, 256, 0, stream>>>(counts, exsc, bsum);
    k_scan_top<<<1, 256, 0, stream>>>(bsum, boff);
    k_finalize_off<<<(Nn + 255) / 256, 256, 0, stream>>>(exsc, boff, row_off, cursor);
    k_scatter<<<(ETot + 255) / 256, 256, 0, stream>>>(srcA, dstA, cursor, csr_src);

    // ---- layer 1 ----
    dim3 g1((Nn + 127) / 128, 2);
    k_gemm1_mfma<<<g1, 256, 0, stream>>>(xhi, xlo, wt2, h1b, Nn);
    k_alpha_b<H1, C1h, HC1><<<(Nn * H1 + 255) / 256, 256, 0, stream>>>(
        h1b, as1, ad1, asrc1, adst1, Nn);
    k_gat_aggr1<<<(int)(((size_t)Nn * 64 + 255) / 256), 256, 0, stream>>>(
        row_off, csr_src, asrc1, adst1, h1b, b1, o1hi, o1lo);

    // ---- layer 2 ----
    k_gemm2_mfma<<<(Nn + 127) / 128, 256, 0, stream>>>(o1hi, o1lo, wt2b, h2, Nn);
    k_alpha_b<1, C2, S2><<<(Nn + 255) / 256, 256, 0, stream>>>(
        h2, as2, ad2, asrc2, adst2, Nn);
    k_gat_aggr2<<<(int)(((size_t)Nn * 64 + 255) / 256), 256, 0, stream>>>(
        row_off, csr_src, asrc2, adst2, h2, b2, outp);
}

// Round 9
// 286.507 us; speedup vs baseline: 1.0530x; 1.0530x over previous
//
#include <hip/hip_runtime.h>
#include <cstdint>
#include <cstddef>

// ---------------- problem constants (from setup_inputs) ----------------
constexpr int Nn   = 50000;            // nodes
constexpr int Ee   = 800000;           // edges (without self loops)
constexpr int ETot = Ee + Nn;          // 850000 with self loops
constexpr int H1   = 8;                // heads layer 1
constexpr int C1h  = 32;               // channels/head layer 1
constexpr int HC1  = 256;              // H1*C1h
constexpr int C2   = 40;               // classes (layer 2, 1 head)
constexpr int S2   = 64;               // padded h2 row stride (shorts) = 128 B
constexpr float SLOPE = 0.2f;          // leaky_relu negative slope
constexpr int NB_SCAN = (Nn + 255) / 256;   // 196 scan blocks

typedef __attribute__((ext_vector_type(8))) short bf16x8;   // 8 bf16 (4 VGPRs)
typedef __attribute__((ext_vector_type(4))) float f32x4;    // MFMA accumulator

__device__ __forceinline__ ushort f2bf(float f) {           // RNE f32->bf16
    uint u = __float_as_uint(f);
    u += 0x7fffu + ((u >> 16) & 1u);
    return (ushort)(u >> 16);
}
__device__ __forceinline__ float bf2f(ushort b) {
    return __uint_as_float(((uint)b) << 16);
}

// async global->LDS, 16 B per lane; LDS dest = wave-uniform base + lane*16
__device__ __forceinline__ void gload16(const void* g, void* lds) {
    typedef const __attribute__((address_space(1))) unsigned int GU;
    typedef __attribute__((address_space(3))) unsigned int LU;
    __builtin_amdgcn_global_load_lds((GU*)g, (LU*)lds, 16, 0, 0);
}

// ====== merged prep: x split (bf16 hi/lo) | W1 pack | W2 pack | dst hist =====
__global__ void k_prep(const float* __restrict__ x, ushort* __restrict__ xhi,
                       ushort* __restrict__ xlo, const float* __restrict__ w1,
                       ushort* __restrict__ WT2, const float* __restrict__ w2,
                       ushort* __restrict__ WT2b, const int* __restrict__ dstA,
                       int* __restrict__ counts) {
    int t = blockIdx.x * blockDim.x + threadIdx.x;
    constexpr int n4 = Nn * HC1 / 4;                  // 3.2M
    if (t < n4) {
        float4 v = *(const float4*)(x + (size_t)t * 4);
        ushort4 h, l;
        h.x = f2bf(v.x); l.x = f2bf(v.x - bf2f(h.x));
        h.y = f2bf(v.y); l.y = f2bf(v.y - bf2f(h.y));
        h.z = f2bf(v.z); l.z = f2bf(v.z - bf2f(h.z));
        h.w = f2bf(v.w); l.w = f2bf(v.w - bf2f(h.w));
        *(ushort4*)(xhi + (size_t)t * 4) = h;
        *(ushort4*)(xlo + (size_t)t * 4) = l;
    }
    if (t < ETot) {
        int d = (t < Ee) ? dstA[t] : t - Ee;
        atomicAdd(&counts[d], 1);
    }
    if (t < 256 * 256) {
        int k = t >> 8, col = t & 255;
        float w = w1[(size_t)k * 256 + col];
        ushort h = f2bf(w), l = f2bf(w - bf2f(h));
        int kb = k >> 3, kr = k & 7;
        WT2[((size_t)(kb)      * 256 + col) * 8 + kr] = h;
        WT2[((size_t)(kb + 32) * 256 + col) * 8 + kr] = h;
        WT2[((size_t)(kb + 64) * 256 + col) * 8 + kr] = l;
    }
    if (t < 256 * 48) {
        int k = t / 48, col = t % 48;
        float w = (col < C2) ? w2[(size_t)k * C2 + col] : 0.f;
        ushort h = f2bf(w), l = f2bf(w - bf2f(h));
        int kb = k >> 3, kr = k & 7;
        WT2b[((size_t)(kb)      * 48 + col) * 8 + kr] = h;
        WT2b[((size_t)(kb + 32) * 48 + col) * 8 + kr] = h;
        WT2b[((size_t)(kb + 64) * 48 + col) * 8 + kr] = l;
    }
}

// ================= CSR build (scan -> scatter) =================
__global__ __launch_bounds__(256) void k_scan_block(const int* __restrict__ counts,
                                                    int* __restrict__ exsc,
                                                    int* __restrict__ bsum) {
    __shared__ int sm[256];
    int i = blockIdx.x * 256 + threadIdx.x;
    int v = (i < Nn) ? counts[i] : 0;
    sm[threadIdx.x] = v;
    __syncthreads();
#pragma unroll
    for (int off = 1; off < 256; off <<= 1) {
        int t = (threadIdx.x >= off) ? sm[threadIdx.x - off] : 0;
        __syncthreads();
        sm[threadIdx.x] += t;
        __syncthreads();
    }
    if (i < Nn) exsc[i] = sm[threadIdx.x] - v;
    if (threadIdx.x == 255) bsum[blockIdx.x] = sm[255];
}

__global__ __launch_bounds__(256) void k_scan_top(const int* __restrict__ bsum,
                                                  int* __restrict__ boff) {
    __shared__ int sm[256];
    int t = threadIdx.x;
    int v = (t < NB_SCAN) ? bsum[t] : 0;
    sm[t] = v;
    __syncthreads();
#pragma unroll
    for (int off = 1; off < 256; off <<= 1) {
        int x = (t >= off) ? sm[t - off] : 0;
        __syncthreads();
        sm[t] += x;
        __syncthreads();
    }
    if (t < NB_SCAN) boff[t] = sm[t] - v;
}

__global__ void k_finalize_off(const int* __restrict__ exsc, const int* __restrict__ boff,
                               int* __restrict__ row_off, int* __restrict__ cursor) {
    int i = blockIdx.x * blockDim.x + threadIdx.x;
    if (i < Nn) {
        int r = exsc[i] + boff[i >> 8];
        row_off[i] = r;
        cursor[i] = r;
    }
    if (i == 0) row_off[Nn] = ETot;
}

__global__ void k_scatter(const int* __restrict__ srcA, const int* __restrict__ dstA,
                          int* __restrict__ cursor, int* __restrict__ csr_src) {
    int e = blockIdx.x * blockDim.x + threadIdx.x;
    if (e >= ETot) return;
    int s, d;
    if (e < Ee) { s = srcA[e]; d = dstA[e]; } else { s = e - Ee; d = s; }
    int pos = atomicAdd(&cursor[d], 1);
    csr_src[pos] = s;
}

// ========== GEMM1 (MFMA bf16, split precision): [M,768']x[768',256] ==========
// 128x256 tile (full output width, A fetched once), BK=32, 512 thr / 8 waves
// (2x4 wave grid, 64x64 each). global_load_lds dbuf, one barrier per K-step.
// Fused epilogue: h1b (bf16) + alpha projections asrc1/adst1 [node*8+head].
__global__ __launch_bounds__(512, 4) void k_gemm1_mfma(const ushort* __restrict__ xhi,
                                                       const ushort* __restrict__ xlo,
                                                       const ushort* __restrict__ WT2,
                                                       ushort* __restrict__ h1b,
                                                       const float* __restrict__ a_s,
                                                       const float* __restrict__ a_d,
                                                       float* __restrict__ asrc1,
                                                       float* __restrict__ adst1, int M) {
    constexpr int BK = 32, KD = 768;
    __shared__ __align__(16) ushort As[2][128 * BK];   //  8 KB: (kc*128+row)*8
    __shared__ __align__(16) ushort Bs[2][256 * BK];   // 16 KB: (kc*256+col)*8
    const int tid = threadIdx.x;
    const int bm = blockIdx.x * 128;
    const int lane = tid & 63;
    const int wid = tid >> 6;
    const int wm = wid >> 2, wn = wid & 3;             // 2x4 wave grid
    const int l16 = lane & 15, lk = lane >> 4;

    // A staging: thread t -> (kc = t>>7, row = t&127), 1 x 16 B
    const int sakc = tid >> 7, sarow = tid & 127;
    int arow = bm + sarow; arow = arow < M ? arow : M - 1;

    auto stage = [&](int buf, int k0) {
        const ushort* xsec; int ks;
        if (k0 < 256)      { xsec = xhi; ks = k0; }
        else if (k0 < 512) { xsec = xlo; ks = k0 - 256; }
        else               { xsec = xhi; ks = k0 - 512; }
        gload16(xsec + (size_t)arow * 256 + ks + sakc * 8, As[buf] + tid * 8);
        // B tile: 16 KB contiguous in packed WT2 starting at (k0>>3)*256*8
        const ushort* bbase = WT2 + (size_t)(k0 >> 3) * 256 * 8;
        gload16(bbase + (size_t)tid * 8,         Bs[buf] + tid * 8);
        gload16(bbase + (size_t)(512 + tid) * 8, Bs[buf] + (512 + tid) * 8);
    };

    f32x4 acc[4][4] = {};
    stage(0, 0);
    __syncthreads();                          // drains vmcnt(0) + barrier
    int buf = 0;
    for (int k0 = 0; k0 < KD; k0 += BK) {
        if (k0 + BK < KD) stage(buf ^ 1, k0 + BK);
        bf16x8 a[4], b[4];
#pragma unroll
        for (int m = 0; m < 4; m++)
            a[m] = *(const bf16x8*)(As[buf] + (lk * 128 + wm * 64 + m * 16 + l16) * 8);
#pragma unroll
        for (int n = 0; n < 4; n++)
            b[n] = *(const bf16x8*)(Bs[buf] + (lk * 256 + wn * 64 + n * 16 + l16) * 8);
#pragma unroll
        for (int m = 0; m < 4; m++)
#pragma unroll
            for (int n = 0; n < 4; n++)
                acc[m][n] = __builtin_amdgcn_mfma_f32_16x16x32_bf16(a[m], b[n], acc[m][n], 0, 0, 0);
        __syncthreads();                      // drains this iter's stage too
        buf ^= 1;
    }
    // ---- epilogue: h1b store + fused alpha (per-row dot with a_s/a_d) ----
    // lane's cols: wn*64 + n*16 + l16 (n=0..3); head t = wn*2 + (n>>1).
    float as_v[4], ad_v[4];
#pragma unroll
    for (int n = 0; n < 4; n++) {
        int col = wn * 64 + n * 16 + l16;
        as_v[n] = a_s[col];
        ad_v[n] = a_d[col];
    }
#pragma unroll
    for (int m = 0; m < 4; m++) {
#pragma unroll
        for (int j = 0; j < 4; j++) {
            int row = bm + wm * 64 + m * 16 + lk * 4 + j;
            float ps0 = acc[m][0][j] * as_v[0] + acc[m][1][j] * as_v[1];
            float ps1 = acc[m][2][j] * as_v[2] + acc[m][3][j] * as_v[3];
            float pd0 = acc[m][0][j] * ad_v[0] + acc[m][1][j] * ad_v[1];
            float pd1 = acc[m][2][j] * ad_v[2] + acc[m][3][j] * ad_v[3];
#pragma unroll
            for (int off = 1; off < 16; off <<= 1) {
                ps0 += __shfl_xor(ps0, off);
                ps1 += __shfl_xor(ps1, off);
                pd0 += __shfl_xor(pd0, off);
                pd1 += __shfl_xor(pd1, off);
            }
            if (row < M) {
#pragma unroll
                for (int n = 0; n < 4; n++)
                    h1b[(size_t)row * 256 + wn * 64 + n * 16 + l16] = f2bf(acc[m][n][j]);
                if (l16 == 0) {
                    asrc1[(size_t)row * H1 + wn * 2]     = ps0;
                    asrc1[(size_t)row * H1 + wn * 2 + 1] = ps1;
                    adst1[(size_t)row * H1 + wn * 2]     = pd0;
                    adst1[(size_t)row * H1 + wn * 2 + 1] = pd1;
                }
            }
        }
    }
}

// ========== GEMM2 (MFMA bf16, split precision): [M,768']x[768',48] ==========
// 128-row tile, 4 waves x 32 rows (acc[2][3]); fused alpha2 epilogue.
__global__ __launch_bounds__(256, 4) void k_gemm2_mfma(const ushort* __restrict__ hi,
                                                       const ushort* __restrict__ lo,
                                                       const ushort* __restrict__ WT,
                                                       ushort* __restrict__ h2,
                                                       const float* __restrict__ a_s,
                                                       const float* __restrict__ a_d,
                                                       float* __restrict__ asrc2,
                                                       float* __restrict__ adst2, int M) {
    constexpr int BK = 32, KD = 768;
    __shared__ __align__(16) ushort As[2][128 * BK];   // (kc*128+row)*8
    __shared__ __align__(16) ushort Bs[2][48 * BK];    // idx*8, idx = kc*48+col
    const int tid = threadIdx.x;
    const int bm = blockIdx.x * 128;
    const int lane = tid & 63;
    const int w = tid >> 6;
    const int l16 = lane & 15, lk = lane >> 4;

    const int srow = tid & 127, skc = tid >> 7;
    int arow = bm + srow; arow = arow < M ? arow : M - 1;

    auto stage = [&](int buf, int k0) {
        const ushort* xsec; int ks;
        if (k0 < 256)      { xsec = hi; ks = k0; }
        else if (k0 < 512) { xsec = lo; ks = k0 - 256; }
        else               { xsec = hi; ks = k0 - 512; }
        const ushort* a_base = xsec + (size_t)arow * 256 + ks;
        gload16(a_base + skc * 8,       As[buf] + tid * 8);
        gload16(a_base + (skc + 2) * 8, As[buf] + (256 + tid) * 8);
        if (tid < 192)   // B tile: linear 3 KB copy (packed layout)
            gload16(WT + ((size_t)(k0 >> 3) * 48 + tid) * 8, Bs[buf] + tid * 8);
    };

    f32x4 acc[2][3] = {};
    stage(0, 0);
    __syncthreads();
    int buf = 0;
    for (int k0 = 0; k0 < KD; k0 += BK) {
        if (k0 + BK < KD) stage(buf ^ 1, k0 + BK);
        bf16x8 a2[2], b2[3];
#pragma unroll
        for (int m = 0; m < 2; m++)
            a2[m] = *(const bf16x8*)(As[buf] + (lk * 128 + w * 32 + m * 16 + l16) * 8);
#pragma unroll
        for (int n = 0; n < 3; n++)
            b2[n] = *(const bf16x8*)(Bs[buf] + (lk * 48 + n * 16 + l16) * 8);
#pragma unroll
        for (int m = 0; m < 2; m++)
#pragma unroll
            for (int n = 0; n < 3; n++)
                acc[m][n] = __builtin_amdgcn_mfma_f32_16x16x32_bf16(a2[m], b2[n], acc[m][n], 0, 0, 0);
        __syncthreads();
        buf ^= 1;
    }
    // ---- epilogue: h2 store (padded stride) + fused alpha2 ----
    float asv[3], adv[3];
#pragma unroll
    for (int n = 0; n < 3; n++) {
        int col = n * 16 + l16;
        asv[n] = (col < C2) ? a_s[col] : 0.f;
        adv[n] = (col < C2) ? a_d[col] : 0.f;
    }
#pragma unroll
    for (int m = 0; m < 2; m++) {
#pragma unroll
        for (int j = 0; j < 4; j++) {
            int row = bm + w * 32 + m * 16 + lk * 4 + j;
            float ps = acc[m][0][j] * asv[0] + acc[m][1][j] * asv[1] + acc[m][2][j] * asv[2];
            float pd = acc[m][0][j] * adv[0] + acc[m][1][j] * adv[1] + acc[m][2][j] * adv[2];
#pragma unroll
            for (int off = 1; off < 16; off <<= 1) {
                ps += __shfl_xor(ps, off);
                pd += __shfl_xor(pd, off);
            }
            if (row < M) {
#pragma unroll
                for (int n = 0; n < 3; n++)
                    h2[(size_t)row * S2 + n * 16 + l16] = f2bf(acc[m][n][j]);
                if (l16 == 0) { asrc2[row] = ps; adst2[row] = pd; }
            }
        }
    }
}

// ======== layer-1 aggregation: half-wave per edge, 4-deep unrolled ========
__global__ __launch_bounds__(256) void k_gat_aggr1(const int* __restrict__ row_off,
                                                   const int* __restrict__ csr_src,
                                                   const float* __restrict__ asrc,
                                                   const float* __restrict__ adst,
                                                   const ushort* __restrict__ h1b,
                                                   const float* __restrict__ bias,
                                                   ushort* __restrict__ o_hi,
                                                   ushort* __restrict__ o_lo) {
    int wid = (blockIdx.x * 256 + threadIdx.x) >> 6;   // node id
    if (wid >= Nn) return;
    int lane = threadIdx.x & 63;
    int half = lane >> 5, l32 = lane & 31;
    int head = l32 >> 2;                 // 4 lanes per head, 8 ch each
    int c0 = l32 * 8;
    int beg = row_off[wid], end = row_off[wid + 1];
    float ad = adst[(size_t)wid * H1 + head];
    float acc[8] = {};
    float sump = 0.f;
    int i = beg + half;
    for (; i + 6 < end; i += 8) {        // 4 edges per half per iter
        int s0 = csr_src[i],     s1 = csr_src[i + 2];
        int s2 = csr_src[i + 4], s3 = csr_src[i + 6];
        float a0 = asrc[(size_t)s0 * H1 + head], a1 = asrc[(size_t)s1 * H1 + head];
        float a2 = asrc[(size_t)s2 * H1 + head], a3 = asrc[(size_t)s3 * H1 + head];
        bf16x8 v0 = *(const bf16x8*)(h1b + (size_t)s0 * HC1 + c0);
        bf16x8 v1 = *(const bf16x8*)(h1b + (size_t)s1 * HC1 + c0);
        bf16x8 v2 = *(const bf16x8*)(h1b + (size_t)s2 * HC1 + c0);
        bf16x8 v3 = *(const bf16x8*)(h1b + (size_t)s3 * HC1 + c0);
        float l0 = a0 + ad; l0 = l0 > 0.f ? l0 : SLOPE * l0;
        float l1 = a1 + ad; l1 = l1 > 0.f ? l1 : SLOPE * l1;
        float l2 = a2 + ad; l2 = l2 > 0.f ? l2 : SLOPE * l2;
        float l3 = a3 + ad; l3 = l3 > 0.f ? l3 : SLOPE * l3;
        float p0 = __expf(l0), p1 = __expf(l1), p2 = __expf(l2), p3 = __expf(l3);
        sump += (p0 + p1) + (p2 + p3);
#pragma unroll
        for (int j = 0; j < 8; j++)
            acc[j] += (p0 * bf2f((ushort)v0[j]) + p1 * bf2f((ushort)v1[j])) +
                      (p2 * bf2f((ushort)v2[j]) + p3 * bf2f((ushort)v3[j]));
    }
    for (; i < end; i += 2) {
        int s = csr_src[i];
        float a = asrc[(size_t)s * H1 + head];
        bf16x8 v = *(const bf16x8*)(h1b + (size_t)s * HC1 + c0);
        float l = a + ad; l = l > 0.f ? l : SLOPE * l;
        float p = __expf(l);
        sump += p;
#pragma unroll
        for (int j = 0; j < 8; j++) acc[j] += p * bf2f((ushort)v[j]);
    }
    // merge the two half-waves
    sump += __shfl_xor(sump, 32);
#pragma unroll
    for (int j = 0; j < 8; j++) acc[j] += __shfl_xor(acc[j], 32);
    if (half) return;
    float inv = 1.f / sump;              // degree >= 1 (self-loop)
    float4 b0 = *(const float4*)(bias + c0);
    float4 b1 = *(const float4*)(bias + c0 + 4);
    float bb[8] = {b0.x, b0.y, b0.z, b0.w, b1.x, b1.y, b1.z, b1.w};
    uint4 uh, ul;
    uint* uhp = (uint*)&uh; uint* ulp = (uint*)&ul;
#pragma unroll
    for (int q = 0; q < 4; q++) {
        float r0 = acc[2 * q] * inv + bb[2 * q];
        float r1 = acc[2 * q + 1] * inv + bb[2 * q + 1];
        r0 = r0 > 0.f ? r0 : __expf(r0) - 1.f;     // fused ELU
        r1 = r1 > 0.f ? r1 : __expf(r1) - 1.f;
        ushort h0 = f2bf(r0), h1v = f2bf(r1);
        ushort l0 = f2bf(r0 - bf2f(h0)), l1v = f2bf(r1 - bf2f(h1v));
        uhp[q] = (uint)h0 | ((uint)h1v << 16);
        ulp[q] = (uint)l0 | ((uint)l1v << 16);
    }
    *(uint4*)(o_hi + (size_t)wid * HC1 + c0) = uh;
    *(uint4*)(o_lo + (size_t)wid * HC1 + c0) = ul;
}

// ======== layer-2 aggregation: wave/node, lanes 0..39, padded bf16 h2 =======
__global__ __launch_bounds__(256) void k_gat_aggr2(const int* __restrict__ row_off,
                                                   const int* __restrict__ csr_src,
                                                   const float* __restrict__ asrc,
                                                   const float* __restrict__ adst,
                                                   const ushort* __restrict__ h2,
                                                   const float* __restrict__ bias,
                                                   float* __restrict__ out) {
    int wid = (blockIdx.x * 256 + threadIdx.x) >> 6;
    if (wid >= Nn) return;
    int lane = threadIdx.x & 63;
    int cl = lane < C2 ? lane : C2 - 1;            // clamp: lanes 40..63 read c39
    int beg = row_off[wid], end = row_off[wid + 1];
    float ad = adst[wid];
    float acc = 0.f, sump = 0.f;
    int i = beg;
    for (; i + 3 < end; i += 4) {
        int s0 = csr_src[i], s1 = csr_src[i + 1], s2 = csr_src[i + 2], s3 = csr_src[i + 3];
        float a0 = asrc[s0], a1 = asrc[s1], a2 = asrc[s2], a3 = asrc[s3];
        float v0 = bf2f(h2[(size_t)s0 * S2 + cl]);
        float v1 = bf2f(h2[(size_t)s1 * S2 + cl]);
        float v2 = bf2f(h2[(size_t)s2 * S2 + cl]);
        float v3 = bf2f(h2[(size_t)s3 * S2 + cl]);
        float l0 = a0 + ad; l0 = l0 > 0.f ? l0 : SLOPE * l0;
        float l1 = a1 + ad; l1 = l1 > 0.f ? l1 : SLOPE * l1;
        float l2 = a2 + ad; l2 = l2 > 0.f ? l2 : SLOPE * l2;
        float l3 = a3 + ad; l3 = l3 > 0.f ? l3 : SLOPE * l3;
        float p0 = __expf(l0), p1 = __expf(l1), p2 = __expf(l2), p3 = __expf(l3);
        sump += (p0 + p1) + (p2 + p3);
        acc += p0 * v0 + p1 * v1 + p2 * v2 + p3 * v3;
    }
    for (; i < end; i++) {
        int s = csr_src[i];
        float l = asrc[s] + ad;
        l = l > 0.f ? l : SLOPE * l;
        float pe = __expf(l);
        sump += pe;
        acc += pe * bf2f(h2[(size_t)s * S2 + cl]);
    }
    if (lane < C2) out[(size_t)wid * C2 + lane] = acc / sump + bias[lane];
}

// ---------------- launch ----------------
extern "C" void kernel_launch(void* const* d_in, const int* in_sizes, int n_in,
                              void* d_out, int out_size, void* d_ws, size_t ws_size,
                              hipStream_t stream) {
    const float* x   = (const float*)d_in[0];
    const int*   ei  = (const int*)d_in[1];
    const float* w1  = (const float*)d_in[2];
    const float* as1 = (const float*)d_in[3];
    const float* ad1 = (const float*)d_in[4];
    const float* b1  = (const float*)d_in[5];
    const float* w2  = (const float*)d_in[6];
    const float* as2 = (const float*)d_in[7];
    const float* ad2 = (const float*)d_in[8];
    const float* b2  = (const float*)d_in[9];
    float* outp = (float*)d_out;

    const int* srcA = ei;
    const int* dstA = ei + Ee;

    char* W = (char*)d_ws;
    size_t o = 0;
    auto allocB = [&](size_t bytes) { void* p = W + o; o += (bytes + 255) & ~(size_t)255; return p; };

    ushort* xhi   = (ushort*)allocB((size_t)Nn * HC1 * 2);   // 25.6 MB
    ushort* xlo   = (ushort*)allocB((size_t)Nn * HC1 * 2);   // 25.6 MB
    ushort* o1hi  = xhi;   // alias: out1 hi/lo reuse xhi/xlo after GEMM1
    ushort* o1lo  = xlo;
    ushort* wt2   = (ushort*)allocB((size_t)768 * 256 * 2);  // packed W1'
    ushort* wt2b  = (ushort*)allocB((size_t)768 * 48 * 2);   // packed W2'
    ushort* h1b   = (ushort*)allocB((size_t)Nn * HC1 * 2);   // 25.6 MB
    ushort* h2    = (ushort*)allocB((size_t)Nn * S2 * 2);    // 6.4 MB (padded)
    float*  asrc1 = (float*)allocB((size_t)Nn * H1 * 4);
    float*  adst1 = (float*)allocB((size_t)Nn * H1 * 4);
    float*  asrc2 = (float*)allocB((size_t)Nn * 4);
    float*  adst2 = (float*)allocB((size_t)Nn * 4);
    int* counts   = (int*)allocB((size_t)Nn * 4);
    int* exsc     = (int*)allocB((size_t)Nn * 4);
    int* bsum     = (int*)allocB(256 * 4);
    int* boff     = (int*)allocB(256 * 4);
    int* row_off  = (int*)allocB((size_t)(Nn + 1) * 4);
    int* cursor   = (int*)allocB((size_t)Nn * 4);
    int* csr_src  = (int*)allocB((size_t)ETot * 4);

    // ---- prep (split + weight packs + degree histogram, one dispatch) ----
    hipMemsetAsync(counts, 0, (size_t)Nn * sizeof(int), stream);
    k_prep<<<(Nn * HC1 / 4 + 255) / 256, 256, 0, stream>>>(
        x, xhi, xlo, w1, wt2, w2, wt2b, dstA, counts);

    // ---- CSR build (graph shared by both layers) ----
    k_scan_block<<<NB_SCAN, 256, 0, stream>>>(counts, exsc, bsum);
    k_scan_top<<<1, 256, 0, stream>>>(bsum, boff);
    k_finalize_off<<<(Nn + 255) / 256, 256, 0, stream>>>(exsc, boff, row_off, cursor);
    k_scatter<<<(ETot + 255) / 256, 256, 0, stream>>>(srcA, dstA, cursor, csr_src);

    // ---- layer 1 (alpha fused into GEMM epilogue) ----
    k_gemm1_mfma<<<(Nn + 127) / 128, 512, 0, stream>>>(
        xhi, xlo, wt2, h1b, as1, ad1, asrc1, adst1, Nn);
    k_gat_aggr1<<<(int)(((size_t)Nn * 64 + 255) / 256), 256, 0, stream>>>(
        row_off, csr_src, asrc1, adst1, h1b, b1, o1hi, o1lo);

    // ---- layer 2 (alpha fused into GEMM epilogue) ----
    k_gemm2_mfma<<<(Nn + 127) / 128, 256, 0, stream>>>(
        o1hi, o1lo, wt2b, h2, as2, ad2, asrc2, adst2, Nn);
    k_gat_aggr2<<<(int)(((size_t)Nn * 64 + 255) / 256), 256, 0, stream>>>(
        row_off, csr_src, asrc2, adst2, h2, b2, outp);
}

// Round 10
// 285.162 us; speedup vs baseline: 1.0580x; 1.0047x over previous
//
#include <hip/hip_runtime.h>
#include <cstdint>
#include <cstddef>

// ---------------- problem constants (from setup_inputs) ----------------
constexpr int Nn   = 50000;            // nodes
constexpr int Ee   = 800000;           // edges (without self loops)
constexpr int ETot = Ee + Nn;          // 850000 with self loops
constexpr int H1   = 8;                // heads layer 1
constexpr int C1h  = 32;               // channels/head layer 1
constexpr int HC1  = 256;              // H1*C1h
constexpr int C2   = 40;               // classes (layer 2, 1 head)
constexpr int S2   = 64;               // padded h2 row stride (shorts) = 128 B
constexpr float SLOPE = 0.2f;          // leaky_relu negative slope
constexpr int NB_SCAN = (Nn + 255) / 256;   // 196 scan blocks

typedef __attribute__((ext_vector_type(8))) short bf16x8;   // 8 bf16 (4 VGPRs)
typedef __attribute__((ext_vector_type(4))) float f32x4;    // MFMA accumulator

__device__ __forceinline__ ushort f2bf(float f) {           // RNE f32->bf16
    uint u = __float_as_uint(f);
    u += 0x7fffu + ((u >> 16) & 1u);
    return (ushort)(u >> 16);
}
__device__ __forceinline__ float bf2f(ushort b) {
    return __uint_as_float(((uint)b) << 16);
}

// async global->LDS, 16 B per lane; LDS dest = wave-uniform base + lane*16
__device__ __forceinline__ void gload16(const void* g, void* lds) {
    typedef const __attribute__((address_space(1))) unsigned int GU;
    typedef __attribute__((address_space(3))) unsigned int LU;
    __builtin_amdgcn_global_load_lds((GU*)g, (LU*)lds, 16, 0, 0);
}

// ====== merged prep: x split (bf16 hi/lo) | W1 pack | W2 pack | dst hist =====
__global__ void k_prep(const float* __restrict__ x, ushort* __restrict__ xhi,
                       ushort* __restrict__ xlo, const float* __restrict__ w1,
                       ushort* __restrict__ WT2, const float* __restrict__ w2,
                       ushort* __restrict__ WT2b, const int* __restrict__ dstA,
                       int* __restrict__ counts) {
    int t = blockIdx.x * blockDim.x + threadIdx.x;
    constexpr int n4 = Nn * HC1 / 4;                  // 3.2M
    if (t < n4) {
        float4 v = *(const float4*)(x + (size_t)t * 4);
        ushort4 h, l;
        h.x = f2bf(v.x); l.x = f2bf(v.x - bf2f(h.x));
        h.y = f2bf(v.y); l.y = f2bf(v.y - bf2f(h.y));
        h.z = f2bf(v.z); l.z = f2bf(v.z - bf2f(h.z));
        h.w = f2bf(v.w); l.w = f2bf(v.w - bf2f(h.w));
        *(ushort4*)(xhi + (size_t)t * 4) = h;
        *(ushort4*)(xlo + (size_t)t * 4) = l;
    }
    if (t < ETot) {
        int d = (t < Ee) ? dstA[t] : t - Ee;
        atomicAdd(&counts[d], 1);
    }
    if (t < 256 * 256) {
        int k = t >> 8, col = t & 255;
        float w = w1[(size_t)k * 256 + col];
        ushort h = f2bf(w), l = f2bf(w - bf2f(h));
        int kb = k >> 3, kr = k & 7;
        WT2[((size_t)(kb)      * 256 + col) * 8 + kr] = h;
        WT2[((size_t)(kb + 32) * 256 + col) * 8 + kr] = h;
        WT2[((size_t)(kb + 64) * 256 + col) * 8 + kr] = l;
    }
    if (t < 256 * 48) {
        int k = t / 48, col = t % 48;
        float w = (col < C2) ? w2[(size_t)k * C2 + col] : 0.f;
        ushort h = f2bf(w), l = f2bf(w - bf2f(h));
        int kb = k >> 3, kr = k & 7;
        WT2b[((size_t)(kb)      * 48 + col) * 8 + kr] = h;
        WT2b[((size_t)(kb + 32) * 48 + col) * 8 + kr] = h;
        WT2b[((size_t)(kb + 64) * 48 + col) * 8 + kr] = l;
    }
}

// ================= CSR build (scan -> merged top+finalize -> scatter) ========
__global__ __launch_bounds__(256) void k_scan_block(const int* __restrict__ counts,
                                                    int* __restrict__ exsc,
                                                    int* __restrict__ bsum) {
    __shared__ int sm[256];
    int i = blockIdx.x * 256 + threadIdx.x;
    int v = (i < Nn) ? counts[i] : 0;
    sm[threadIdx.x] = v;
    __syncthreads();
#pragma unroll
    for (int off = 1; off < 256; off <<= 1) {
        int t = (threadIdx.x >= off) ? sm[threadIdx.x - off] : 0;
        __syncthreads();
        sm[threadIdx.x] += t;
        __syncthreads();
    }
    if (i < Nn) exsc[i] = sm[threadIdx.x] - v;
    if (threadIdx.x == 255) bsum[blockIdx.x] = sm[255];
}

// every block redundantly top-scans bsum (196 ints) in LDS, then finalizes
// its own 256 nodes (row_off + cursor).
__global__ __launch_bounds__(256) void k_finalize2(const int* __restrict__ exsc,
                                                   const int* __restrict__ bsum,
                                                   int* __restrict__ row_off,
                                                   int* __restrict__ cursor) {
    __shared__ int sm[256];
    int t = threadIdx.x;
    int v = (t < NB_SCAN) ? bsum[t] : 0;
    sm[t] = v;
    __syncthreads();
#pragma unroll
    for (int off = 1; off < 256; off <<= 1) {
        int x = (t >= off) ? sm[t - off] : 0;
        __syncthreads();
        sm[t] += x;
        __syncthreads();
    }
    int i = blockIdx.x * 256 + t;
    if (i < Nn) {
        int r = exsc[i] + sm[blockIdx.x] - bsum[blockIdx.x];  // exclusive boff
        row_off[i] = r;
        cursor[i] = r;
    }
    if (i == 0) row_off[Nn] = ETot;
}

__global__ void k_scatter(const int* __restrict__ srcA, const int* __restrict__ dstA,
                          int* __restrict__ cursor, int* __restrict__ csr_src) {
    int e = blockIdx.x * blockDim.x + threadIdx.x;
    if (e >= ETot) return;
    int s, d;
    if (e < Ee) { s = srcA[e]; d = dstA[e]; } else { s = e - Ee; d = s; }
    int pos = atomicAdd(&cursor[d], 1);
    csr_src[pos] = s;
}

// ========== GEMM1 (MFMA bf16, split precision): [M,768']x[768',256] ==========
// 64x256 tile (full width, A fetched once; 782 blocks ~ 3/CU balanced), BK=32,
// 256 thr / 4 waves (wave w = col block w*64; 64x64 acc[4][4] each).
// global_load_lds dbuf, one barrier per K-step. Fused alpha epilogue.
__global__ __launch_bounds__(256, 4) void k_gemm1_mfma(const ushort* __restrict__ xhi,
                                                       const ushort* __restrict__ xlo,
                                                       const ushort* __restrict__ WT2,
                                                       ushort* __restrict__ h1b,
                                                       const float* __restrict__ a_s,
                                                       const float* __restrict__ a_d,
                                                       float* __restrict__ asrc1,
                                                       float* __restrict__ adst1, int M) {
    constexpr int BK = 32, KD = 768;
    __shared__ __align__(16) ushort As[2][64 * BK];    //  4 KB: (kc*64+row)*8
    __shared__ __align__(16) ushort Bs[2][256 * BK];   // 16 KB: (kc*256+col)*8
    const int tid = threadIdx.x;
    const int bm = blockIdx.x * 64;
    const int lane = tid & 63;
    const int w = tid >> 6;                            // wave = col block
    const int l16 = lane & 15, lk = lane >> 4;

    // A staging: thread t -> (kc = t>>6, row = t&63): dest idx = t
    const int sakc = tid >> 6, sarow = tid & 63;
    int arow = bm + sarow; arow = arow < M ? arow : M - 1;

    auto stage = [&](int buf, int k0) {
        const ushort* xsec; int ks;
        if (k0 < 256)      { xsec = xhi; ks = k0; }
        else if (k0 < 512) { xsec = xlo; ks = k0 - 256; }
        else               { xsec = xhi; ks = k0 - 512; }
        gload16(xsec + (size_t)arow * 256 + ks + sakc * 8, As[buf] + tid * 8);
        // B tile: 16 KB contiguous in packed WT2 at (k0>>3)*256*8
        const ushort* bbase = WT2 + (size_t)(k0 >> 3) * 256 * 8;
#pragma unroll
        for (int q = 0; q < 4; q++)
            gload16(bbase + (size_t)(q * 256 + tid) * 8, Bs[buf] + (q * 256 + tid) * 8);
    };

    f32x4 acc[4][4] = {};
    stage(0, 0);
    __syncthreads();                          // drains vmcnt(0) + barrier
    int buf = 0;
    for (int k0 = 0; k0 < KD; k0 += BK) {
        if (k0 + BK < KD) stage(buf ^ 1, k0 + BK);
        bf16x8 a[4], b[4];
#pragma unroll
        for (int m = 0; m < 4; m++)
            a[m] = *(const bf16x8*)(As[buf] + (lk * 64 + m * 16 + l16) * 8);
#pragma unroll
        for (int n = 0; n < 4; n++)
            b[n] = *(const bf16x8*)(Bs[buf] + (lk * 256 + w * 64 + n * 16 + l16) * 8);
#pragma unroll
        for (int m = 0; m < 4; m++)
#pragma unroll
            for (int n = 0; n < 4; n++)
                acc[m][n] = __builtin_amdgcn_mfma_f32_16x16x32_bf16(a[m], b[n], acc[m][n], 0, 0, 0);
        __syncthreads();                      // drains this iter's stage too
        buf ^= 1;
    }
    // ---- epilogue: h1b store + fused alpha (heads 2w, 2w+1) ----
    float as_v[4], ad_v[4];
#pragma unroll
    for (int n = 0; n < 4; n++) {
        int col = w * 64 + n * 16 + l16;
        as_v[n] = a_s[col];
        ad_v[n] = a_d[col];
    }
#pragma unroll
    for (int m = 0; m < 4; m++) {
#pragma unroll
        for (int j = 0; j < 4; j++) {
            int row = bm + m * 16 + lk * 4 + j;
            float ps0 = acc[m][0][j] * as_v[0] + acc[m][1][j] * as_v[1];
            float ps1 = acc[m][2][j] * as_v[2] + acc[m][3][j] * as_v[3];
            float pd0 = acc[m][0][j] * ad_v[0] + acc[m][1][j] * ad_v[1];
            float pd1 = acc[m][2][j] * ad_v[2] + acc[m][3][j] * ad_v[3];
#pragma unroll
            for (int off = 1; off < 16; off <<= 1) {
                ps0 += __shfl_xor(ps0, off);
                ps1 += __shfl_xor(ps1, off);
                pd0 += __shfl_xor(pd0, off);
                pd1 += __shfl_xor(pd1, off);
            }
            if (row < M) {
#pragma unroll
                for (int n = 0; n < 4; n++)
                    h1b[(size_t)row * 256 + w * 64 + n * 16 + l16] = f2bf(acc[m][n][j]);
                if (l16 == 0) {
                    asrc1[(size_t)row * H1 + w * 2]     = ps0;
                    asrc1[(size_t)row * H1 + w * 2 + 1] = ps1;
                    adst1[(size_t)row * H1 + w * 2]     = pd0;
                    adst1[(size_t)row * H1 + w * 2 + 1] = pd1;
                }
            }
        }
    }
}

// ========== GEMM2 (MFMA bf16, split precision): [M,768']x[768',48] ==========
// 64-row tile (782 blocks), 4 waves x 16 rows (acc[1][3]); fused alpha2.
__global__ __launch_bounds__(256, 4) void k_gemm2_mfma(const ushort* __restrict__ hi,
                                                       const ushort* __restrict__ lo,
                                                       const ushort* __restrict__ WT,
                                                       ushort* __restrict__ h2,
                                                       const float* __restrict__ a_s,
                                                       const float* __restrict__ a_d,
                                                       float* __restrict__ asrc2,
                                                       float* __restrict__ adst2, int M) {
    constexpr int BK = 32, KD = 768;
    __shared__ __align__(16) ushort As[2][64 * BK];    // (kc*64+row)*8
    __shared__ __align__(16) ushort Bs[2][48 * BK];    // idx*8, idx = kc*48+col
    const int tid = threadIdx.x;
    const int bm = blockIdx.x * 64;
    const int lane = tid & 63;
    const int w = tid >> 6;
    const int l16 = lane & 15, lk = lane >> 4;

    const int sakc = tid >> 6, sarow = tid & 63;
    int arow = bm + sarow; arow = arow < M ? arow : M - 1;

    auto stage = [&](int buf, int k0) {
        const ushort* xsec; int ks;
        if (k0 < 256)      { xsec = hi; ks = k0; }
        else if (k0 < 512) { xsec = lo; ks = k0 - 256; }
        else               { xsec = hi; ks = k0 - 512; }
        gload16(xsec + (size_t)arow * 256 + ks + sakc * 8, As[buf] + tid * 8);
        if (tid < 192)   // B tile: linear 3 KB copy (packed layout)
            gload16(WT + ((size_t)(k0 >> 3) * 48 + tid) * 8, Bs[buf] + tid * 8);
    };

    f32x4 acc[3] = {};
    stage(0, 0);
    __syncthreads();
    int buf = 0;
    for (int k0 = 0; k0 < KD; k0 += BK) {
        if (k0 + BK < KD) stage(buf ^ 1, k0 + BK);
        bf16x8 a2, b2[3];
        a2 = *(const bf16x8*)(As[buf] + (lk * 64 + w * 16 + l16) * 8);
#pragma unroll
        for (int n = 0; n < 3; n++)
            b2[n] = *(const bf16x8*)(Bs[buf] + (lk * 48 + n * 16 + l16) * 8);
#pragma unroll
        for (int n = 0; n < 3; n++)
            acc[n] = __builtin_amdgcn_mfma_f32_16x16x32_bf16(a2, b2[n], acc[n], 0, 0, 0);
        __syncthreads();
        buf ^= 1;
    }
    // ---- epilogue: h2 store (padded stride) + fused alpha2 ----
    float asv[3], adv[3];
#pragma unroll
    for (int n = 0; n < 3; n++) {
        int col = n * 16 + l16;
        asv[n] = (col < C2) ? a_s[col] : 0.f;
        adv[n] = (col < C2) ? a_d[col] : 0.f;
    }
#pragma unroll
    for (int j = 0; j < 4; j++) {
        int row = bm + w * 16 + lk * 4 + j;
        float ps = acc[0][j] * asv[0] + acc[1][j] * asv[1] + acc[2][j] * asv[2];
        float pd = acc[0][j] * adv[0] + acc[1][j] * adv[1] + acc[2][j] * adv[2];
#pragma unroll
        for (int off = 1; off < 16; off <<= 1) {
            ps += __shfl_xor(ps, off);
            pd += __shfl_xor(pd, off);
        }
        if (row < M) {
#pragma unroll
            for (int n = 0; n < 3; n++)
                h2[(size_t)row * S2 + n * 16 + l16] = f2bf(acc[n][j]);
            if (l16 == 0) { asrc2[row] = ps; adst2[row] = pd; }
        }
    }
}

// ======== layer-1 aggregation: half-wave per edge, 4-deep unrolled ========
__global__ __launch_bounds__(256) void k_gat_aggr1(const int* __restrict__ row_off,
                                                   const int* __restrict__ csr_src,
                                                   const float* __restrict__ asrc,
                                                   const float* __restrict__ adst,
                                                   const ushort* __restrict__ h1b,
                                                   const float* __restrict__ bias,
                                                   ushort* __restrict__ o_hi,
                                                   ushort* __restrict__ o_lo) {
    int wid = (blockIdx.x * 256 + threadIdx.x) >> 6;   // node id
    if (wid >= Nn) return;
    int lane = threadIdx.x & 63;
    int half = lane >> 5, l32 = lane & 31;
    int head = l32 >> 2;                 // 4 lanes per head, 8 ch each
    int c0 = l32 * 8;
    int beg = row_off[wid], end = row_off[wid + 1];
    float ad = adst[(size_t)wid * H1 + head];
    float acc[8] = {};
    float sump = 0.f;
    int i = beg + half;
    for (; i + 6 < end; i += 8) {        // 4 edges per half per iter
        int s0 = csr_src[i],     s1 = csr_src[i + 2];
        int s2 = csr_src[i + 4], s3 = csr_src[i + 6];
        float a0 = asrc[(size_t)s0 * H1 + head], a1 = asrc[(size_t)s1 * H1 + head];
        float a2 = asrc[(size_t)s2 * H1 + head], a3 = asrc[(size_t)s3 * H1 + head];
        bf16x8 v0 = *(const bf16x8*)(h1b + (size_t)s0 * HC1 + c0);
        bf16x8 v1 = *(const bf16x8*)(h1b + (size_t)s1 * HC1 + c0);
        bf16x8 v2 = *(const bf16x8*)(h1b + (size_t)s2 * HC1 + c0);
        bf16x8 v3 = *(const bf16x8*)(h1b + (size_t)s3 * HC1 + c0);
        float l0 = a0 + ad; l0 = l0 > 0.f ? l0 : SLOPE * l0;
        float l1 = a1 + ad; l1 = l1 > 0.f ? l1 : SLOPE * l1;
        float l2 = a2 + ad; l2 = l2 > 0.f ? l2 : SLOPE * l2;
        float l3 = a3 + ad; l3 = l3 > 0.f ? l3 : SLOPE * l3;
        float p0 = __expf(l0), p1 = __expf(l1), p2 = __expf(l2), p3 = __expf(l3);
        sump += (p0 + p1) + (p2 + p3);
#pragma unroll
        for (int j = 0; j < 8; j++)
            acc[j] += (p0 * bf2f((ushort)v0[j]) + p1 * bf2f((ushort)v1[j])) +
                      (p2 * bf2f((ushort)v2[j]) + p3 * bf2f((ushort)v3[j]));
    }
    for (; i < end; i += 2) {
        int s = csr_src[i];
        float a = asrc[(size_t)s * H1 + head];
        bf16x8 v = *(const bf16x8*)(h1b + (size_t)s * HC1 + c0);
        float l = a + ad; l = l > 0.f ? l : SLOPE * l;
        float p = __expf(l);
        sump += p;
#pragma unroll
        for (int j = 0; j < 8; j++) acc[j] += p * bf2f((ushort)v[j]);
    }
    // merge the two half-waves
    sump += __shfl_xor(sump, 32);
#pragma unroll
    for (int j = 0; j < 8; j++) acc[j] += __shfl_xor(acc[j], 32);
    if (half) return;
    float inv = 1.f / sump;              // degree >= 1 (self-loop)
    float4 b0 = *(const float4*)(bias + c0);
    float4 b1 = *(const float4*)(bias + c0 + 4);
    float bb[8] = {b0.x, b0.y, b0.z, b0.w, b1.x, b1.y, b1.z, b1.w};
    uint4 uh, ul;
    uint* uhp = (uint*)&uh; uint* ulp = (uint*)&ul;
#pragma unroll
    for (int q = 0; q < 4; q++) {
        float r0 = acc[2 * q] * inv + bb[2 * q];
        float r1 = acc[2 * q + 1] * inv + bb[2 * q + 1];
        r0 = r0 > 0.f ? r0 : __expf(r0) - 1.f;     // fused ELU
        r1 = r1 > 0.f ? r1 : __expf(r1) - 1.f;
        ushort h0 = f2bf(r0), h1v = f2bf(r1);
        ushort l0 = f2bf(r0 - bf2f(h0)), l1v = f2bf(r1 - bf2f(h1v));
        uhp[q] = (uint)h0 | ((uint)h1v << 16);
        ulp[q] = (uint)l0 | ((uint)l1v << 16);
    }
    *(uint4*)(o_hi + (size_t)wid * HC1 + c0) = uh;
    *(uint4*)(o_lo + (size_t)wid * HC1 + c0) = ul;
}

// ======== layer-2 aggregation: wave/node, lanes 0..39, padded bf16 h2 =======
__global__ __launch_bounds__(256) void k_gat_aggr2(const int* __restrict__ row_off,
                                                   const int* __restrict__ csr_src,
                                                   const float* __restrict__ asrc,
                                                   const float* __restrict__ adst,
                                                   const ushort* __restrict__ h2,
                                                   const float* __restrict__ bias,
                                                   float* __restrict__ out) {
    int wid = (blockIdx.x * 256 + threadIdx.x) >> 6;
    if (wid >= Nn) return;
    int lane = threadIdx.x & 63;
    int cl = lane < C2 ? lane : C2 - 1;            // clamp: lanes 40..63 read c39
    int beg = row_off[wid], end = row_off[wid + 1];
    float ad = adst[wid];
    float acc = 0.f, sump = 0.f;
    int i = beg;
    for (; i + 3 < end; i += 4) {
        int s0 = csr_src[i], s1 = csr_src[i + 1], s2 = csr_src[i + 2], s3 = csr_src[i + 3];
        float a0 = asrc[s0], a1 = asrc[s1], a2 = asrc[s2], a3 = asrc[s3];
        float v0 = bf2f(h2[(size_t)s0 * S2 + cl]);
        float v1 = bf2f(h2[(size_t)s1 * S2 + cl]);
        float v2 = bf2f(h2[(size_t)s2 * S2 + cl]);
        float v3 = bf2f(h2[(size_t)s3 * S2 + cl]);
        float l0 = a0 + ad; l0 = l0 > 0.f ? l0 : SLOPE * l0;
        float l1 = a1 + ad; l1 = l1 > 0.f ? l1 : SLOPE * l1;
        float l2 = a2 + ad; l2 = l2 > 0.f ? l2 : SLOPE * l2;
        float l3 = a3 + ad; l3 = l3 > 0.f ? l3 : SLOPE * l3;
        float p0 = __expf(l0), p1 = __expf(l1), p2 = __expf(l2), p3 = __expf(l3);
        sump += (p0 + p1) + (p2 + p3);
        acc += p0 * v0 + p1 * v1 + p2 * v2 + p3 * v3;
    }
    for (; i < end; i++) {
        int s = csr_src[i];
        float l = asrc[s] + ad;
        l = l > 0.f ? l : SLOPE * l;
        float pe = __expf(l);
        sump += pe;
        acc += pe * bf2f(h2[(size_t)s * S2 + cl]);
    }
    if (lane < C2) out[(size_t)wid * C2 + lane] = acc / sump + bias[lane];
}

// ---------------- launch ----------------
extern "C" void kernel_launch(void* const* d_in, const int* in_sizes, int n_in,
                              void* d_out, int out_size, void* d_ws, size_t ws_size,
                              hipStream_t stream) {
    const float* x   = (const float*)d_in[0];
    const int*   ei  = (const int*)d_in[1];
    const float* w1  = (const float*)d_in[2];
    const float* as1 = (const float*)d_in[3];
    const float* ad1 = (const float*)d_in[4];
    const float* b1  = (const float*)d_in[5];
    const float* w2  = (const float*)d_in[6];
    const float* as2 = (const float*)d_in[7];
    const float* ad2 = (const float*)d_in[8];
    const float* b2  = (const float*)d_in[9];
    float* outp = (float*)d_out;

    const int* srcA = ei;
    const int* dstA = ei + Ee;

    char* W = (char*)d_ws;
    size_t o = 0;
    auto allocB = [&](size_t bytes) { void* p = W + o; o += (bytes + 255) & ~(size_t)255; return p; };

    ushort* xhi   = (ushort*)allocB((size_t)Nn * HC1 * 2);   // 25.6 MB
    ushort* xlo   = (ushort*)allocB((size_t)Nn * HC1 * 2);   // 25.6 MB
    ushort* o1hi  = xhi;   // alias: out1 hi/lo reuse xhi/xlo after GEMM1
    ushort* o1lo  = xlo;
    ushort* wt2   = (ushort*)allocB((size_t)768 * 256 * 2);  // packed W1'
    ushort* wt2b  = (ushort*)allocB((size_t)768 * 48 * 2);   // packed W2'
    ushort* h1b   = (ushort*)allocB((size_t)Nn * HC1 * 2);   // 25.6 MB
    ushort* h2    = (ushort*)allocB((size_t)Nn * S2 * 2);    // 6.4 MB (padded)
    float*  asrc1 = (float*)allocB((size_t)Nn * H1 * 4);
    float*  adst1 = (float*)allocB((size_t)Nn * H1 * 4);
    float*  asrc2 = (float*)allocB((size_t)Nn * 4);
    float*  adst2 = (float*)allocB((size_t)Nn * 4);
    int* counts   = (int*)allocB((size_t)Nn * 4);
    int* exsc     = (int*)allocB((size_t)Nn * 4);
    int* bsum     = (int*)allocB(256 * 4);
    int* row_off  = (int*)allocB((size_t)(Nn + 1) * 4);
    int* cursor   = (int*)allocB((size_t)Nn * 4);
    int* csr_src  = (int*)allocB((size_t)ETot * 4);

    // ---- prep (split + weight packs + degree histogram, one dispatch) ----
    hipMemsetAsync(counts, 0, (size_t)Nn * sizeof(int), stream);
    k_prep<<<(Nn * HC1 / 4 + 255) / 256, 256, 0, stream>>>(
        x, xhi, xlo, w1, wt2, w2, wt2b, dstA, counts);

    // ---- CSR build (graph shared by both layers) ----
    k_scan_block<<<NB_SCAN, 256, 0, stream>>>(counts, exsc, bsum);
    k_finalize2<<<NB_SCAN, 256, 0, stream>>>(exsc, bsum, row_off, cursor);
    k_scatter<<<(ETot + 255) / 256, 256, 0, stream>>>(srcA, dstA, cursor, csr_src);

    // ---- layer 1 (alpha fused into GEMM epilogue) ----
    k_gemm1_mfma<<<(Nn + 63) / 64, 256, 0, stream>>>(
        xhi, xlo, wt2, h1b, as1, ad1, asrc1, adst1, Nn);
    k_gat_aggr1<<<(int)(((size_t)Nn * 64 + 255) / 256), 256, 0, stream>>>(
        row_off, csr_src, asrc1, adst1, h1b, b1, o1hi, o1lo);

    // ---- layer 2 (alpha fused into GEMM epilogue) ----
    k_gemm2_mfma<<<(Nn + 63) / 64, 256, 0, stream>>>(
        o1hi, o1lo, wt2b, h2, as2, ad2, asrc2, adst2, Nn);
    k_gat_aggr2<<<(int)(((size_t)Nn * 64 + 255) / 256), 256, 0, stream>>>(
        row_off, csr_src, asrc2, adst2, h2, b2, outp);
}

// Round 11
// 273.878 us; speedup vs baseline: 1.1016x; 1.0412x over previous
//
#include <hip/hip_runtime.h>
#include <cstdint>
#include <cstddef>

// ---------------- problem constants (from setup_inputs) ----------------
constexpr int Nn   = 50000;            // nodes
constexpr int Ee   = 800000;           // edges (without self loops)
constexpr int ETot = Ee + Nn;          // 850000 with self loops
constexpr int H1   = 8;                // heads layer 1
constexpr int C1h  = 32;               // channels/head layer 1
constexpr int HC1  = 256;              // H1*C1h
constexpr int C2   = 40;               // classes (layer 2, 1 head)
constexpr int S2   = 64;               // padded h2 row stride (shorts) = 128 B
constexpr float SLOPE = 0.2f;          // leaky_relu negative slope
constexpr int NB_SCAN = (Nn + 255) / 256;   // 196 scan blocks

typedef __attribute__((ext_vector_type(8))) short bf16x8;   // 8 bf16 (4 VGPRs)
typedef __attribute__((ext_vector_type(4))) float f32x4;    // MFMA accumulator

__device__ __forceinline__ ushort f2bf(float f) {           // RNE f32->bf16
    uint u = __float_as_uint(f);
    u += 0x7fffu + ((u >> 16) & 1u);
    return (ushort)(u >> 16);
}
__device__ __forceinline__ float bf2f(ushort b) {
    return __uint_as_float(((uint)b) << 16);
}

// async global->LDS, 16 B per lane; LDS dest = wave-uniform base + lane*16
__device__ __forceinline__ void gload16(const void* g, void* lds) {
    typedef const __attribute__((address_space(1))) unsigned int GU;
    typedef __attribute__((address_space(3))) unsigned int LU;
    __builtin_amdgcn_global_load_lds((GU*)g, (LU*)lds, 16, 0, 0);
}

// ====== merged prep: x split (bf16 hi/lo) | W1 pack | W2 pack | dst hist =====
// Packed weights, 2 sections [hi; lo]: W1 -> WT2[((kb)*256+col)*8 + kr],
// kb in [0,64): kb<32 = Whi chunks, kb>=32 = Wlo.  W2 likewise with 48 cols.
__global__ void k_prep(const float* __restrict__ x, ushort* __restrict__ xhi,
                       ushort* __restrict__ xlo, const float* __restrict__ w1,
                       ushort* __restrict__ WT2, const float* __restrict__ w2,
                       ushort* __restrict__ WT2b, const int* __restrict__ dstA,
                       int* __restrict__ counts) {
    int t = blockIdx.x * blockDim.x + threadIdx.x;
    constexpr int n4 = Nn * HC1 / 4;                  // 3.2M
    if (t < n4) {
        float4 v = *(const float4*)(x + (size_t)t * 4);
        ushort4 h, l;
        h.x = f2bf(v.x); l.x = f2bf(v.x - bf2f(h.x));
        h.y = f2bf(v.y); l.y = f2bf(v.y - bf2f(h.y));
        h.z = f2bf(v.z); l.z = f2bf(v.z - bf2f(h.z));
        h.w = f2bf(v.w); l.w = f2bf(v.w - bf2f(h.w));
        *(ushort4*)(xhi + (size_t)t * 4) = h;
        *(ushort4*)(xlo + (size_t)t * 4) = l;
    }
    if (t < ETot) {
        int d = (t < Ee) ? dstA[t] : t - Ee;
        atomicAdd(&counts[d], 1);
    }
    if (t < 256 * 256) {
        int k = t >> 8, col = t & 255;
        float w = w1[(size_t)k * 256 + col];
        ushort h = f2bf(w), l = f2bf(w - bf2f(h));
        int kb = k >> 3, kr = k & 7;
        WT2[((size_t)(kb)      * 256 + col) * 8 + kr] = h;
        WT2[((size_t)(kb + 32) * 256 + col) * 8 + kr] = l;
    }
    if (t < 256 * 48) {
        int k = t / 48, col = t % 48;
        float w = (col < C2) ? w2[(size_t)k * C2 + col] : 0.f;
        ushort h = f2bf(w), l = f2bf(w - bf2f(h));
        int kb = k >> 3, kr = k & 7;
        WT2b[((size_t)(kb)      * 48 + col) * 8 + kr] = h;
        WT2b[((size_t)(kb + 32) * 48 + col) * 8 + kr] = l;
    }
}

// ================= CSR build (scan -> merged top+finalize -> scatter) ========
__global__ __launch_bounds__(256) void k_scan_block(const int* __restrict__ counts,
                                                    int* __restrict__ exsc,
                                                    int* __restrict__ bsum) {
    __shared__ int sm[256];
    int i = blockIdx.x * 256 + threadIdx.x;
    int v = (i < Nn) ? counts[i] : 0;
    sm[threadIdx.x] = v;
    __syncthreads();
#pragma unroll
    for (int off = 1; off < 256; off <<= 1) {
        int t = (threadIdx.x >= off) ? sm[threadIdx.x - off] : 0;
        __syncthreads();
        sm[threadIdx.x] += t;
        __syncthreads();
    }
    if (i < Nn) exsc[i] = sm[threadIdx.x] - v;
    if (threadIdx.x == 255) bsum[blockIdx.x] = sm[255];
}

__global__ __launch_bounds__(256) void k_finalize2(const int* __restrict__ exsc,
                                                   const int* __restrict__ bsum,
                                                   int* __restrict__ row_off,
                                                   int* __restrict__ cursor) {
    __shared__ int sm[256];
    int t = threadIdx.x;
    int v = (t < NB_SCAN) ? bsum[t] : 0;
    sm[t] = v;
    __syncthreads();
#pragma unroll
    for (int off = 1; off < 256; off <<= 1) {
        int x = (t >= off) ? sm[t - off] : 0;
        __syncthreads();
        sm[t] += x;
        __syncthreads();
    }
    int i = blockIdx.x * 256 + t;
    if (i < Nn) {
        int r = exsc[i] + sm[blockIdx.x] - bsum[blockIdx.x];  // exclusive boff
        row_off[i] = r;
        cursor[i] = r;
    }
    if (i == 0) row_off[Nn] = ETot;
}

__global__ void k_scatter(const int* __restrict__ srcA, const int* __restrict__ dstA,
                          int* __restrict__ cursor, int* __restrict__ csr_src) {
    int e = blockIdx.x * blockDim.x + threadIdx.x;
    if (e >= ETot) return;
    int s, d;
    if (e < Ee) { s = srcA[e]; d = dstA[e]; } else { s = e - Ee; d = s; }
    int pos = atomicAdd(&cursor[d], 1);
    csr_src[pos] = s;
}

// ========== GEMM1 (MFMA bf16, split precision): h = xhi(Whi+Wlo) + xlo*Whi ===
// 64x256 tile, 4 waves (wave w = col block w*64, acc[4][4]).  A: gload16 dbuf,
// 16 steps (8 hi chunks used vs BOTH Whi and Wlo, then 8 lo chunks vs Whi).
// B fragments read DIRECTLY from L2-resident packed WT2 (256 KB) - no LDS.
// Fused alpha epilogue.
__global__ __launch_bounds__(256, 3) void k_gemm1_mfma(const ushort* __restrict__ xhi,
                                                       const ushort* __restrict__ xlo,
                                                       const ushort* __restrict__ WT2,
                                                       ushort* __restrict__ h1b,
                                                       const float* __restrict__ a_s,
                                                       const float* __restrict__ a_d,
                                                       float* __restrict__ asrc1,
                                                       float* __restrict__ adst1, int M) {
    __shared__ __align__(16) ushort As[2][64 * 32];    // 4 KB each: (kc*64+row)*8
    const int tid = threadIdx.x;
    const int bm = blockIdx.x * 64;
    const int lane = tid & 63;
    const int w = tid >> 6;                            // wave = col block
    const int l16 = lane & 15, lk = lane >> 4;

    const int sakc = tid >> 6, sarow = tid & 63;       // stage slot
    int arow = bm + sarow; arow = arow < M ? arow : M - 1;

    auto stageA = [&](int buf, int t) {
        const ushort* xsec = (t < 8) ? xhi : xlo;
        int ks = (t & 7) * 32;
        gload16(xsec + (size_t)arow * 256 + ks + sakc * 8, As[buf] + tid * 8);
    };

    f32x4 acc[4][4] = {};
    stageA(0, 0);
    __syncthreads();
    int buf = 0;
    for (int t = 0; t < 16; t++) {
        if (t + 1 < 16) stageA(buf ^ 1, t + 1);
        int kc = t & 7;
        bf16x8 a[4];
#pragma unroll
        for (int m = 0; m < 4; m++)
            a[m] = *(const bf16x8*)(As[buf] + (lk * 64 + m * 16 + l16) * 8);
        // B-hi fragments straight from global (kb = kc*4 + lk)
        bf16x8 bh[4];
#pragma unroll
        for (int n = 0; n < 4; n++)
            bh[n] = *(const bf16x8*)(WT2 +
                ((size_t)(kc * 4 + lk) * 256 + w * 64 + n * 16 + l16) * 8);
#pragma unroll
        for (int m = 0; m < 4; m++)
#pragma unroll
            for (int n = 0; n < 4; n++)
                acc[m][n] = __builtin_amdgcn_mfma_f32_16x16x32_bf16(a[m], bh[n], acc[m][n], 0, 0, 0);
        if (t < 8) {     // hi phase: also multiply by W-lo (kb = 32 + kc*4 + lk)
            bf16x8 bl[4];
#pragma unroll
            for (int n = 0; n < 4; n++)
                bl[n] = *(const bf16x8*)(WT2 +
                    ((size_t)(32 + kc * 4 + lk) * 256 + w * 64 + n * 16 + l16) * 8);
#pragma unroll
            for (int m = 0; m < 4; m++)
#pragma unroll
                for (int n = 0; n < 4; n++)
                    acc[m][n] = __builtin_amdgcn_mfma_f32_16x16x32_bf16(a[m], bl[n], acc[m][n], 0, 0, 0);
        }
        __syncthreads();
        buf ^= 1;
    }
    // ---- epilogue: h1b store + fused alpha (heads 2w, 2w+1) ----
    float as_v[4], ad_v[4];
#pragma unroll
    for (int n = 0; n < 4; n++) {
        int col = w * 64 + n * 16 + l16;
        as_v[n] = a_s[col];
        ad_v[n] = a_d[col];
    }
#pragma unroll
    for (int m = 0; m < 4; m++) {
#pragma unroll
        for (int j = 0; j < 4; j++) {
            int row = bm + m * 16 + lk * 4 + j;
            float ps0 = acc[m][0][j] * as_v[0] + acc[m][1][j] * as_v[1];
            float ps1 = acc[m][2][j] * as_v[2] + acc[m][3][j] * as_v[3];
            float pd0 = acc[m][0][j] * ad_v[0] + acc[m][1][j] * ad_v[1];
            float pd1 = acc[m][2][j] * ad_v[2] + acc[m][3][j] * ad_v[3];
#pragma unroll
            for (int off = 1; off < 16; off <<= 1) {
                ps0 += __shfl_xor(ps0, off);
                ps1 += __shfl_xor(ps1, off);
                pd0 += __shfl_xor(pd0, off);
                pd1 += __shfl_xor(pd1, off);
            }
            if (row < M) {
#pragma unroll
                for (int n = 0; n < 4; n++)
                    h1b[(size_t)row * 256 + w * 64 + n * 16 + l16] = f2bf(acc[m][n][j]);
                if (l16 == 0) {
                    asrc1[(size_t)row * H1 + w * 2]     = ps0;
                    asrc1[(size_t)row * H1 + w * 2 + 1] = ps1;
                    adst1[(size_t)row * H1 + w * 2]     = pd0;
                    adst1[(size_t)row * H1 + w * 2 + 1] = pd1;
                }
            }
        }
    }
}

// ========== GEMM2 (MFMA bf16, split precision): [M]x[48 cols] ==========
// 64-row tile, 4 waves x 16 rows (acc[3]); B2 (48 KB) direct from L2.
__global__ __launch_bounds__(256, 4) void k_gemm2_mfma(const ushort* __restrict__ hi,
                                                       const ushort* __restrict__ lo,
                                                       const ushort* __restrict__ WT,
                                                       ushort* __restrict__ h2,
                                                       const float* __restrict__ a_s,
                                                       const float* __restrict__ a_d,
                                                       float* __restrict__ asrc2,
                                                       float* __restrict__ adst2, int M) {
    __shared__ __align__(16) ushort As[2][64 * 32];
    const int tid = threadIdx.x;
    const int bm = blockIdx.x * 64;
    const int lane = tid & 63;
    const int w = tid >> 6;
    const int l16 = lane & 15, lk = lane >> 4;

    const int sakc = tid >> 6, sarow = tid & 63;
    int arow = bm + sarow; arow = arow < M ? arow : M - 1;

    auto stageA = [&](int buf, int t) {
        const ushort* xsec = (t < 8) ? hi : lo;
        int ks = (t & 7) * 32;
        gload16(xsec + (size_t)arow * 256 + ks + sakc * 8, As[buf] + tid * 8);
    };

    f32x4 acc[3] = {};
    stageA(0, 0);
    __syncthreads();
    int buf = 0;
    for (int t = 0; t < 16; t++) {
        if (t + 1 < 16) stageA(buf ^ 1, t + 1);
        int kc = t & 7;
        bf16x8 a2 = *(const bf16x8*)(As[buf] + (lk * 64 + w * 16 + l16) * 8);
        bf16x8 bh[3];
#pragma unroll
        for (int n = 0; n < 3; n++)
            bh[n] = *(const bf16x8*)(WT +
                ((size_t)(kc * 4 + lk) * 48 + n * 16 + l16) * 8);
#pragma unroll
        for (int n = 0; n < 3; n++)
            acc[n] = __builtin_amdgcn_mfma_f32_16x16x32_bf16(a2, bh[n], acc[n], 0, 0, 0);
        if (t < 8) {
            bf16x8 bl[3];
#pragma unroll
            for (int n = 0; n < 3; n++)
                bl[n] = *(const bf16x8*)(WT +
                    ((size_t)(32 + kc * 4 + lk) * 48 + n * 16 + l16) * 8);
#pragma unroll
            for (int n = 0; n < 3; n++)
                acc[n] = __builtin_amdgcn_mfma_f32_16x16x32_bf16(a2, bl[n], acc[n], 0, 0, 0);
        }
        __syncthreads();
        buf ^= 1;
    }
    // ---- epilogue: h2 store (padded stride) + fused alpha2 ----
    float asv[3], adv[3];
#pragma unroll
    for (int n = 0; n < 3; n++) {
        int col = n * 16 + l16;
        asv[n] = (col < C2) ? a_s[col] : 0.f;
        adv[n] = (col < C2) ? a_d[col] : 0.f;
    }
#pragma unroll
    for (int j = 0; j < 4; j++) {
        int row = bm + w * 16 + lk * 4 + j;
        float ps = acc[0][j] * asv[0] + acc[1][j] * asv[1] + acc[2][j] * asv[2];
        float pd = acc[0][j] * adv[0] + acc[1][j] * adv[1] + acc[2][j] * adv[2];
#pragma unroll
        for (int off = 1; off < 16; off <<= 1) {
            ps += __shfl_xor(ps, off);
            pd += __shfl_xor(pd, off);
        }
        if (row < M) {
#pragma unroll
            for (int n = 0; n < 3; n++)
                h2[(size_t)row * S2 + n * 16 + l16] = f2bf(acc[n][j]);
            if (l16 == 0) { asrc2[row] = ps; adst2[row] = pd; }
        }
    }
}

// ======== layer-1 aggregation: half-wave per edge, 4-deep unrolled ========
__global__ __launch_bounds__(256) void k_gat_aggr1(const int* __restrict__ row_off,
                                                   const int* __restrict__ csr_src,
                                                   const float* __restrict__ asrc,
                                                   const float* __restrict__ adst,
                                                   const ushort* __restrict__ h1b,
                                                   const float* __restrict__ bias,
                                                   ushort* __restrict__ o_hi,
                                                   ushort* __restrict__ o_lo) {
    int wid = (blockIdx.x * 256 + threadIdx.x) >> 6;   // node id
    if (wid >= Nn) return;
    int lane = threadIdx.x & 63;
    int half = lane >> 5, l32 = lane & 31;
    int head = l32 >> 2;                 // 4 lanes per head, 8 ch each
    int c0 = l32 * 8;
    int beg = row_off[wid], end = row_off[wid + 1];
    float ad = adst[(size_t)wid * H1 + head];
    float acc[8] = {};
    float sump = 0.f;
    int i = beg + half;
    for (; i + 6 < end; i += 8) {        // 4 edges per half per iter
        int s0 = csr_src[i],     s1 = csr_src[i + 2];
        int s2 = csr_src[i + 4], s3 = csr_src[i + 6];
        float a0 = asrc[(size_t)s0 * H1 + head], a1 = asrc[(size_t)s1 * H1 + head];
        float a2 = asrc[(size_t)s2 * H1 + head], a3 = asrc[(size_t)s3 * H1 + head];
        bf16x8 v0 = *(const bf16x8*)(h1b + (size_t)s0 * HC1 + c0);
        bf16x8 v1 = *(const bf16x8*)(h1b + (size_t)s1 * HC1 + c0);
        bf16x8 v2 = *(const bf16x8*)(h1b + (size_t)s2 * HC1 + c0);
        bf16x8 v3 = *(const bf16x8*)(h1b + (size_t)s3 * HC1 + c0);
        float l0 = a0 + ad; l0 = l0 > 0.f ? l0 : SLOPE * l0;
        float l1 = a1 + ad; l1 = l1 > 0.f ? l1 : SLOPE * l1;
        float l2 = a2 + ad; l2 = l2 > 0.f ? l2 : SLOPE * l2;
        float l3 = a3 + ad; l3 = l3 > 0.f ? l3 : SLOPE * l3;
        float p0 = __expf(l0), p1 = __expf(l1), p2 = __expf(l2), p3 = __expf(l3);
        sump += (p0 + p1) + (p2 + p3);
#pragma unroll
        for (int j = 0; j < 8; j++)
            acc[j] += (p0 * bf2f((ushort)v0[j]) + p1 * bf2f((ushort)v1[j])) +
                      (p2 * bf2f((ushort)v2[j]) + p3 * bf2f((ushort)v3[j]));
    }
    for (; i < end; i += 2) {
        int s = csr_src[i];
        float a = asrc[(size_t)s * H1 + head];
        bf16x8 v = *(const bf16x8*)(h1b + (size_t)s * HC1 + c0);
        float l = a + ad; l = l > 0.f ? l : SLOPE * l;
        float p = __expf(l);
        sump += p;
#pragma unroll
        for (int j = 0; j < 8; j++) acc[j] += p * bf2f((ushort)v[j]);
    }
    // merge the two half-waves
    sump += __shfl_xor(sump, 32);
#pragma unroll
    for (int j = 0; j < 8; j++) acc[j] += __shfl_xor(acc[j], 32);
    if (half) return;
    float inv = 1.f / sump;              // degree >= 1 (self-loop)
    float4 b0 = *(const float4*)(bias + c0);
    float4 b1 = *(const float4*)(bias + c0 + 4);
    float bb[8] = {b0.x, b0.y, b0.z, b0.w, b1.x, b1.y, b1.z, b1.w};
    uint4 uh, ul;
    uint* uhp = (uint*)&uh; uint* ulp = (uint*)&ul;
#pragma unroll
    for (int q = 0; q < 4; q++) {
        float r0 = acc[2 * q] * inv + bb[2 * q];
        float r1 = acc[2 * q + 1] * inv + bb[2 * q + 1];
        r0 = r0 > 0.f ? r0 : __expf(r0) - 1.f;     // fused ELU
        r1 = r1 > 0.f ? r1 : __expf(r1) - 1.f;
        ushort h0 = f2bf(r0), h1v = f2bf(r1);
        ushort l0 = f2bf(r0 - bf2f(h0)), l1v = f2bf(r1 - bf2f(h1v));
        uhp[q] = (uint)h0 | ((uint)h1v << 16);
        ulp[q] = (uint)l0 | ((uint)l1v << 16);
    }
    *(uint4*)(o_hi + (size_t)wid * HC1 + c0) = uh;
    *(uint4*)(o_lo + (size_t)wid * HC1 + c0) = ul;
}

// ====== layer-2 aggregation: 2 nodes/wave (half-wave/node, 2 ch/lane) ======
__global__ __launch_bounds__(256) void k_gat_aggr2(const int* __restrict__ row_off,
                                                   const int* __restrict__ csr_src,
                                                   const float* __restrict__ asrc,
                                                   const float* __restrict__ adst,
                                                   const ushort* __restrict__ h2,
                                                   const float* __restrict__ bias,
                                                   float* __restrict__ out) {
    int gw = (blockIdx.x * 256 + threadIdx.x) >> 6;    // wave id
    int lane = threadIdx.x & 63;
    int half = lane >> 5, l32 = lane & 31;
    int wid = gw * 2 + half;                           // node id (per half-wave)
    if (wid >= Nn) return;
    int c = l32 * 2;                                   // 2 channels per lane
    int beg = row_off[wid], end = row_off[wid + 1];
    float ad = adst[wid];
    float acc0 = 0.f, acc1 = 0.f, sump = 0.f;
    int i = beg;
    for (; i + 3 < end; i += 4) {
        int s0 = csr_src[i], s1 = csr_src[i + 1], s2 = csr_src[i + 2], s3 = csr_src[i + 3];
        float a0 = asrc[s0], a1 = asrc[s1], a2 = asrc[s2], a3 = asrc[s3];
        uint u0 = *(const uint*)(h2 + (size_t)s0 * S2 + c);
        uint u1 = *(const uint*)(h2 + (size_t)s1 * S2 + c);
        uint u2 = *(const uint*)(h2 + (size_t)s2 * S2 + c);
        uint u3 = *(const uint*)(h2 + (size_t)s3 * S2 + c);
        float l0 = a0 + ad; l0 = l0 > 0.f ? l0 : SLOPE * l0;
        float l1 = a1 + ad; l1 = l1 > 0.f ? l1 : SLOPE * l1;
        float l2 = a2 + ad; l2 = l2 > 0.f ? l2 : SLOPE * l2;
        float l3 = a3 + ad; l3 = l3 > 0.f ? l3 : SLOPE * l3;
        float p0 = __expf(l0), p1 = __expf(l1), p2 = __expf(l2), p3 = __expf(l3);
        sump += (p0 + p1) + (p2 + p3);
        acc0 += p0 * bf2f((ushort)(u0 & 0xffff)) + p1 * bf2f((ushort)(u1 & 0xffff)) +
                p2 * bf2f((ushort)(u2 & 0xffff)) + p3 * bf2f((ushort)(u3 & 0xffff));
        acc1 += p0 * bf2f((ushort)(u0 >> 16)) + p1 * bf2f((ushort)(u1 >> 16)) +
                p2 * bf2f((ushort)(u2 >> 16)) + p3 * bf2f((ushort)(u3 >> 16));
    }
    for (; i < end; i++) {
        int s = csr_src[i];
        float l = asrc[s] + ad;
        l = l > 0.f ? l : SLOPE * l;
        float pe = __expf(l);
        sump += pe;
        uint u = *(const uint*)(h2 + (size_t)s * S2 + c);
        acc0 += pe * bf2f((ushort)(u & 0xffff));
        acc1 += pe * bf2f((ushort)(u >> 16));
    }
    if (c < C2) {
        float inv = 1.f / sump;
        float2 r;
        r.x = acc0 * inv + bias[c];
        r.y = acc1 * inv + bias[c + 1];
        *(float2*)(out + (size_t)wid * C2 + c) = r;
    }
}

// ---------------- launch ----------------
extern "C" void kernel_launch(void* const* d_in, const int* in_sizes, int n_in,
                              void* d_out, int out_size, void* d_ws, size_t ws_size,
                              hipStream_t stream) {
    const float* x   = (const float*)d_in[0];
    const int*   ei  = (const int*)d_in[1];
    const float* w1  = (const float*)d_in[2];
    const float* as1 = (const float*)d_in[3];
    const float* ad1 = (const float*)d_in[4];
    const float* b1  = (const float*)d_in[5];
    const float* w2  = (const float*)d_in[6];
    const float* as2 = (const float*)d_in[7];
    const float* ad2 = (const float*)d_in[8];
    const float* b2  = (const float*)d_in[9];
    float* outp = (float*)d_out;

    const int* srcA = ei;
    const int* dstA = ei + Ee;

    char* W = (char*)d_ws;
    size_t o = 0;
    auto allocB = [&](size_t bytes) { void* p = W + o; o += (bytes + 255) & ~(size_t)255; return p; };

    ushort* xhi   = (ushort*)allocB((size_t)Nn * HC1 * 2);   // 25.6 MB
    ushort* xlo   = (ushort*)allocB((size_t)Nn * HC1 * 2);   // 25.6 MB
    ushort* o1hi  = xhi;   // alias: out1 hi/lo reuse xhi/xlo after GEMM1
    ushort* o1lo  = xlo;
    ushort* wt2   = (ushort*)allocB((size_t)512 * 256 * 2);  // packed W1' (256 KB)
    ushort* wt2b  = (ushort*)allocB((size_t)512 * 48 * 2);   // packed W2' (48 KB)
    ushort* h1b   = (ushort*)allocB((size_t)Nn * HC1 * 2);   // 25.6 MB
    ushort* h2    = (ushort*)allocB((size_t)Nn * S2 * 2);    // 6.4 MB (padded)
    float*  asrc1 = (float*)allocB((size_t)Nn * H1 * 4);
    float*  adst1 = (float*)allocB((size_t)Nn * H1 * 4);
    float*  asrc2 = (float*)allocB((size_t)Nn * 4);
    float*  adst2 = (float*)allocB((size_t)Nn * 4);
    int* counts   = (int*)allocB((size_t)Nn * 4);
    int* exsc     = (int*)allocB((size_t)Nn * 4);
    int* bsum     = (int*)allocB(256 * 4);
    int* row_off  = (int*)allocB((size_t)(Nn + 1) * 4);
    int* cursor   = (int*)allocB((size_t)Nn * 4);
    int* csr_src  = (int*)allocB((size_t)ETot * 4);

    // ---- prep (split + weight packs + degree histogram, one dispatch) ----
    hipMemsetAsync(counts, 0, (size_t)Nn * sizeof(int), stream);
    k_prep<<<(Nn * HC1 / 4 + 255) / 256, 256, 0, stream>>>(
        x, xhi, xlo, w1, wt2, w2, wt2b, dstA, counts);

    // ---- CSR build (graph shared by both layers) ----
    k_scan_block<<<NB_SCAN, 256, 0, stream>>>(counts, exsc, bsum);
    k_finalize2<<<NB_SCAN, 256, 0, stream>>>(exsc, bsum, row_off, cursor);
    k_scatter<<<(ETot + 255) / 256, 256, 0, stream>>>(srcA, dstA, cursor, csr_src);

    // ---- layer 1 (alpha fused into GEMM epilogue) ----
    k_gemm1_mfma<<<(Nn + 63) / 64, 256, 0, stream>>>(
        xhi, xlo, wt2, h1b, as1, ad1, asrc1, adst1, Nn);
    k_gat_aggr1<<<(int)(((size_t)Nn * 64 + 255) / 256), 256, 0, stream>>>(
        row_off, csr_src, asrc1, adst1, h1b, b1, o1hi, o1lo);

    // ---- layer 2 (alpha fused into GEMM epilogue) ----
    k_gemm2_mfma<<<(Nn + 63) / 64, 256, 0, stream>>>(
        o1hi, o1lo, wt2b, h2, as2, ad2, asrc2, adst2, Nn);
    int waves2 = (Nn + 1) / 2;
    k_gat_aggr2<<<(int)(((size_t)waves2 * 64 + 255) / 256), 256, 0, stream>>>(
        row_off, csr_src, asrc2, adst2, h2, b2, outp);
}

// Round 12
// 265.396 us; speedup vs baseline: 1.1368x; 1.0320x over previous
//
#include <hip/hip_runtime.h>
#include <cstdint>
#include <cstddef>

// ---------------- problem constants (from setup_inputs) ----------------
constexpr int Nn   = 50000;            // nodes
constexpr int Ee   = 800000;           // edges (without self loops)
constexpr int ETot = Ee + Nn;          // 850000 with self loops
constexpr int H1   = 8;                // heads layer 1
constexpr int C1h  = 32;               // channels/head layer 1
constexpr int HC1  = 256;              // H1*C1h
constexpr int C2   = 40;               // classes (layer 2, 1 head)
constexpr int S2   = 64;               // padded h2 row stride (shorts) = 128 B
constexpr float SLOPE = 0.2f;          // leaky_relu negative slope
constexpr int NB_SCAN = (Nn + 255) / 256;   // 196 scan blocks

typedef __attribute__((ext_vector_type(8))) short bf16x8;   // 8 bf16 (4 VGPRs)
typedef __attribute__((ext_vector_type(4))) float f32x4;    // MFMA accumulator

__device__ __forceinline__ ushort f2bf(float f) {           // RNE f32->bf16
    uint u = __float_as_uint(f);
    u += 0x7fffu + ((u >> 16) & 1u);
    return (ushort)(u >> 16);
}
__device__ __forceinline__ float bf2f(ushort b) {
    return __uint_as_float(((uint)b) << 16);
}

// async global->LDS, 16 B per lane; LDS dest = wave-uniform base + lane*16
__device__ __forceinline__ void gload16(const void* g, void* lds) {
    typedef const __attribute__((address_space(1))) unsigned int GU;
    typedef __attribute__((address_space(3))) unsigned int LU;
    __builtin_amdgcn_global_load_lds((GU*)g, (LU*)lds, 16, 0, 0);
}

// ====== merged prep: W1 pack | W2 pack | dst hist (x-split removed) =====
// Packed weights, 2 sections [hi; lo]: W1 -> WT2[((kb)*256+col)*8 + kr],
// kb in [0,64): kb<32 = Whi chunks, kb>=32 = Wlo.  W2 likewise with 48 cols.
__global__ void k_prep(const float* __restrict__ w1, ushort* __restrict__ WT2,
                       const float* __restrict__ w2, ushort* __restrict__ WT2b,
                       const int* __restrict__ dstA, int* __restrict__ counts) {
    int t = blockIdx.x * blockDim.x + threadIdx.x;
    if (t < ETot) {
        int d = (t < Ee) ? dstA[t] : t - Ee;
        atomicAdd(&counts[d], 1);
    }
    if (t < 256 * 256) {
        int k = t >> 8, col = t & 255;
        float w = w1[(size_t)k * 256 + col];
        ushort h = f2bf(w), l = f2bf(w - bf2f(h));
        int kb = k >> 3, kr = k & 7;
        WT2[((size_t)(kb)      * 256 + col) * 8 + kr] = h;
        WT2[((size_t)(kb + 32) * 256 + col) * 8 + kr] = l;
    }
    if (t < 256 * 48) {
        int k = t / 48, col = t % 48;
        float w = (col < C2) ? w2[(size_t)k * C2 + col] : 0.f;
        ushort h = f2bf(w), l = f2bf(w - bf2f(h));
        int kb = k >> 3, kr = k & 7;
        WT2b[((size_t)(kb)      * 48 + col) * 8 + kr] = h;
        WT2b[((size_t)(kb + 32) * 48 + col) * 8 + kr] = l;
    }
}

// ================= CSR build (scan -> merged top+finalize -> scatter) ========
__global__ __launch_bounds__(256) void k_scan_block(const int* __restrict__ counts,
                                                    int* __restrict__ exsc,
                                                    int* __restrict__ bsum) {
    __shared__ int sm[256];
    int i = blockIdx.x * 256 + threadIdx.x;
    int v = (i < Nn) ? counts[i] : 0;
    sm[threadIdx.x] = v;
    __syncthreads();
#pragma unroll
    for (int off = 1; off < 256; off <<= 1) {
        int t = (threadIdx.x >= off) ? sm[threadIdx.x - off] : 0;
        __syncthreads();
        sm[threadIdx.x] += t;
        __syncthreads();
    }
    if (i < Nn) exsc[i] = sm[threadIdx.x] - v;
    if (threadIdx.x == 255) bsum[blockIdx.x] = sm[255];
}

__global__ __launch_bounds__(256) void k_finalize2(const int* __restrict__ exsc,
                                                   const int* __restrict__ bsum,
                                                   int* __restrict__ row_off,
                                                   int* __restrict__ cursor) {
    __shared__ int sm[256];
    int t = threadIdx.x;
    int v = (t < NB_SCAN) ? bsum[t] : 0;
    sm[t] = v;
    __syncthreads();
#pragma unroll
    for (int off = 1; off < 256; off <<= 1) {
        int x = (t >= off) ? sm[t - off] : 0;
        __syncthreads();
        sm[t] += x;
        __syncthreads();
    }
    int i = blockIdx.x * 256 + t;
    if (i < Nn) {
        int r = exsc[i] + sm[blockIdx.x] - bsum[blockIdx.x];  // exclusive boff
        row_off[i] = r;
        cursor[i] = r;
    }
    if (i == 0) row_off[Nn] = ETot;
}

__global__ void k_scatter(const int* __restrict__ srcA, const int* __restrict__ dstA,
                          int* __restrict__ cursor, int* __restrict__ csr_src) {
    int e = blockIdx.x * blockDim.x + threadIdx.x;
    if (e >= ETot) return;
    int s, d;
    if (e < Ee) { s = srcA[e]; d = dstA[e]; } else { s = e - Ee; d = s; }
    int pos = atomicAdd(&cursor[d], 1);
    csr_src[pos] = s;
}

// ========== GEMM1 (MFMA bf16, split precision, f32 input direct) ============
// h = xhi(Whi+Wlo) + xlo*Whi.  64x256 tile, 4 waves (wave w = col block).
// A: reg-stage f32 -> convert hi/lo ONCE -> two LDS buffers; 8 K-steps,
// 48 MFMA/wave/step.  B fragments direct from L2-resident packed WT2.
// Fused alpha epilogue.
__global__ __launch_bounds__(256, 3) void k_gemm1_mfma(const float* __restrict__ x,
                                                       const ushort* __restrict__ WT2,
                                                       ushort* __restrict__ h1b,
                                                       const float* __restrict__ a_s,
                                                       const float* __restrict__ a_d,
                                                       float* __restrict__ asrc1,
                                                       float* __restrict__ adst1, int M) {
    __shared__ __align__(16) ushort AsH[2][64 * 32];   // 4 KB each: (kc*64+row)*8
    __shared__ __align__(16) ushort AsL[2][64 * 32];
    const int tid = threadIdx.x;
    const int bm = blockIdx.x * 64;
    const int lane = tid & 63;
    const int w = tid >> 6;                            // wave = col block
    const int l16 = lane & 15, lk = lane >> 4;

    const int sakc = tid >> 6, sarow = tid & 63;       // stage slot (kc, row)
    int arow = bm + sarow; arow = arow < M ? arow : M - 1;
    const float* aptr = x + (size_t)arow * 256 + sakc * 8;
    const int sidx = (sakc * 64 + sarow) * 8;          // LDS dest (shorts)

    float4 f0, f1;
    auto loadA = [&](int t) {
        f0 = *(const float4*)(aptr + t * 32);
        f1 = *(const float4*)(aptr + t * 32 + 4);
    };
    auto cvtWrite = [&](int buf) {
        float ff[8] = {f0.x, f0.y, f0.z, f0.w, f1.x, f1.y, f1.z, f1.w};
        ushort hh[8], ll[8];
#pragma unroll
        for (int j = 0; j < 8; j++) {
            hh[j] = f2bf(ff[j]);
            ll[j] = f2bf(ff[j] - bf2f(hh[j]));
        }
        *(uint4*)(AsH[buf] + sidx) = *(uint4*)hh;
        *(uint4*)(AsL[buf] + sidx) = *(uint4*)ll;
    };

    f32x4 acc[4][4] = {};
    loadA(0);
    cvtWrite(0);
    __syncthreads();
    for (int t = 0; t < 8; t++) {
        int buf = t & 1;
        if (t + 1 < 8) loadA(t + 1);          // loads in flight over MFMA
        bf16x8 aH[4], aL[4];
#pragma unroll
        for (int m = 0; m < 4; m++) {
            aH[m] = *(const bf16x8*)(AsH[buf] + (lk * 64 + m * 16 + l16) * 8);
            aL[m] = *(const bf16x8*)(AsL[buf] + (lk * 64 + m * 16 + l16) * 8);
        }
        bf16x8 bH[4], bL[4];
#pragma unroll
        for (int n = 0; n < 4; n++) {
            bH[n] = *(const bf16x8*)(WT2 +
                ((size_t)(t * 4 + lk) * 256 + w * 64 + n * 16 + l16) * 8);
            bL[n] = *(const bf16x8*)(WT2 +
                ((size_t)(32 + t * 4 + lk) * 256 + w * 64 + n * 16 + l16) * 8);
        }
#pragma unroll
        for (int m = 0; m < 4; m++)
#pragma unroll
            for (int n = 0; n < 4; n++) {
                acc[m][n] = __builtin_amdgcn_mfma_f32_16x16x32_bf16(aH[m], bH[n], acc[m][n], 0, 0, 0);
                acc[m][n] = __builtin_amdgcn_mfma_f32_16x16x32_bf16(aH[m], bL[n], acc[m][n], 0, 0, 0);
                acc[m][n] = __builtin_amdgcn_mfma_f32_16x16x32_bf16(aL[m], bH[n], acc[m][n], 0, 0, 0);
            }
        if (t + 1 < 8) cvtWrite((t + 1) & 1); // write next buf (safe: dbuf)
        __syncthreads();
    }
    // ---- epilogue: h1b store + fused alpha (heads 2w, 2w+1) ----
    float as_v[4], ad_v[4];
#pragma unroll
    for (int n = 0; n < 4; n++) {
        int col = w * 64 + n * 16 + l16;
        as_v[n] = a_s[col];
        ad_v[n] = a_d[col];
    }
#pragma unroll
    for (int m = 0; m < 4; m++) {
#pragma unroll
        for (int j = 0; j < 4; j++) {
            int row = bm + m * 16 + lk * 4 + j;
            float ps0 = acc[m][0][j] * as_v[0] + acc[m][1][j] * as_v[1];
            float ps1 = acc[m][2][j] * as_v[2] + acc[m][3][j] * as_v[3];
            float pd0 = acc[m][0][j] * ad_v[0] + acc[m][1][j] * ad_v[1];
            float pd1 = acc[m][2][j] * ad_v[2] + acc[m][3][j] * ad_v[3];
#pragma unroll
            for (int off = 1; off < 16; off <<= 1) {
                ps0 += __shfl_xor(ps0, off);
                ps1 += __shfl_xor(ps1, off);
                pd0 += __shfl_xor(pd0, off);
                pd1 += __shfl_xor(pd1, off);
            }
            if (row < M) {
#pragma unroll
                for (int n = 0; n < 4; n++)
                    h1b[(size_t)row * 256 + w * 64 + n * 16 + l16] = f2bf(acc[m][n][j]);
                if (l16 == 0) {
                    asrc1[(size_t)row * H1 + w * 2]     = ps0;
                    asrc1[(size_t)row * H1 + w * 2 + 1] = ps1;
                    adst1[(size_t)row * H1 + w * 2]     = pd0;
                    adst1[(size_t)row * H1 + w * 2 + 1] = pd1;
                }
            }
        }
    }
}

// ========== GEMM2 (MFMA bf16, split precision): [M]x[48 cols] ==========
// 64-row tile, 4 waves x 16 rows (acc[3]); B2 (48 KB) direct from L2.
// A from o1hi/o1lo (bf16, made in aggr1 epilogue): 16 steps hi then lo.
__global__ __launch_bounds__(256, 4) void k_gemm2_mfma(const ushort* __restrict__ hi,
                                                       const ushort* __restrict__ lo,
                                                       const ushort* __restrict__ WT,
                                                       ushort* __restrict__ h2,
                                                       const float* __restrict__ a_s,
                                                       const float* __restrict__ a_d,
                                                       float* __restrict__ asrc2,
                                                       float* __restrict__ adst2, int M) {
    __shared__ __align__(16) ushort As[2][64 * 32];
    const int tid = threadIdx.x;
    const int bm = blockIdx.x * 64;
    const int lane = tid & 63;
    const int w = tid >> 6;
    const int l16 = lane & 15, lk = lane >> 4;

    const int sakc = tid >> 6, sarow = tid & 63;
    int arow = bm + sarow; arow = arow < M ? arow : M - 1;

    auto stageA = [&](int buf, int t) {
        const ushort* xsec = (t < 8) ? hi : lo;
        int ks = (t & 7) * 32;
        gload16(xsec + (size_t)arow * 256 + ks + sakc * 8, As[buf] + tid * 8);
    };

    f32x4 acc[3] = {};
    stageA(0, 0);
    __syncthreads();
    int buf = 0;
    for (int t = 0; t < 16; t++) {
        if (t + 1 < 16) stageA(buf ^ 1, t + 1);
        int kc = t & 7;
        bf16x8 a2 = *(const bf16x8*)(As[buf] + (lk * 64 + w * 16 + l16) * 8);
        bf16x8 bh[3];
#pragma unroll
        for (int n = 0; n < 3; n++)
            bh[n] = *(const bf16x8*)(WT +
                ((size_t)(kc * 4 + lk) * 48 + n * 16 + l16) * 8);
#pragma unroll
        for (int n = 0; n < 3; n++)
            acc[n] = __builtin_amdgcn_mfma_f32_16x16x32_bf16(a2, bh[n], acc[n], 0, 0, 0);
        if (t < 8) {
            bf16x8 bl[3];
#pragma unroll
            for (int n = 0; n < 3; n++)
                bl[n] = *(const bf16x8*)(WT +
                    ((size_t)(32 + kc * 4 + lk) * 48 + n * 16 + l16) * 8);
#pragma unroll
            for (int n = 0; n < 3; n++)
                acc[n] = __builtin_amdgcn_mfma_f32_16x16x32_bf16(a2, bl[n], acc[n], 0, 0, 0);
        }
        __syncthreads();
        buf ^= 1;
    }
    // ---- epilogue: h2 store (padded stride) + fused alpha2 ----
    float asv[3], adv[3];
#pragma unroll
    for (int n = 0; n < 3; n++) {
        int col = n * 16 + l16;
        asv[n] = (col < C2) ? a_s[col] : 0.f;
        adv[n] = (col < C2) ? a_d[col] : 0.f;
    }
#pragma unroll
    for (int j = 0; j < 4; j++) {
        int row = bm + w * 16 + lk * 4 + j;
        float ps = acc[0][j] * asv[0] + acc[1][j] * asv[1] + acc[2][j] * asv[2];
        float pd = acc[0][j] * adv[0] + acc[1][j] * adv[1] + acc[2][j] * adv[2];
#pragma unroll
        for (int off = 1; off < 16; off <<= 1) {
            ps += __shfl_xor(ps, off);
            pd += __shfl_xor(pd, off);
        }
        if (row < M) {
#pragma unroll
            for (int n = 0; n < 3; n++)
                h2[(size_t)row * S2 + n * 16 + l16] = f2bf(acc[n][j]);
            if (l16 == 0) { asrc2[row] = ps; adst2[row] = pd; }
        }
    }
}

// ======== layer-1 aggregation: half-wave per edge, 4-deep unrolled ========
__global__ __launch_bounds__(256) void k_gat_aggr1(const int* __restrict__ row_off,
                                                   const int* __restrict__ csr_src,
                                                   const float* __restrict__ asrc,
                                                   const float* __restrict__ adst,
                                                   const ushort* __restrict__ h1b,
                                                   const float* __restrict__ bias,
                                                   ushort* __restrict__ o_hi,
                                                   ushort* __restrict__ o_lo) {
    int wid = (blockIdx.x * 256 + threadIdx.x) >> 6;   // node id
    if (wid >= Nn) return;
    int lane = threadIdx.x & 63;
    int half = lane >> 5, l32 = lane & 31;
    int head = l32 >> 2;                 // 4 lanes per head, 8 ch each
    int c0 = l32 * 8;
    int beg = row_off[wid], end = row_off[wid + 1];
    float ad = adst[(size_t)wid * H1 + head];
    float acc[8] = {};
    float sump = 0.f;
    int i = beg + half;
    for (; i + 6 < end; i += 8) {        // 4 edges per half per iter
        int s0 = csr_src[i],     s1 = csr_src[i + 2];
        int s2 = csr_src[i + 4], s3 = csr_src[i + 6];
        float a0 = asrc[(size_t)s0 * H1 + head], a1 = asrc[(size_t)s1 * H1 + head];
        float a2 = asrc[(size_t)s2 * H1 + head], a3 = asrc[(size_t)s3 * H1 + head];
        bf16x8 v0 = *(const bf16x8*)(h1b + (size_t)s0 * HC1 + c0);
        bf16x8 v1 = *(const bf16x8*)(h1b + (size_t)s1 * HC1 + c0);
        bf16x8 v2 = *(const bf16x8*)(h1b + (size_t)s2 * HC1 + c0);
        bf16x8 v3 = *(const bf16x8*)(h1b + (size_t)s3 * HC1 + c0);
        float l0 = a0 + ad; l0 = l0 > 0.f ? l0 : SLOPE * l0;
        float l1 = a1 + ad; l1 = l1 > 0.f ? l1 : SLOPE * l1;
        float l2 = a2 + ad; l2 = l2 > 0.f ? l2 : SLOPE * l2;
        float l3 = a3 + ad; l3 = l3 > 0.f ? l3 : SLOPE * l3;
        float p0 = __expf(l0), p1 = __expf(l1), p2 = __expf(l2), p3 = __expf(l3);
        sump += (p0 + p1) + (p2 + p3);
#pragma unroll
        for (int j = 0; j < 8; j++)
            acc[j] += (p0 * bf2f((ushort)v0[j]) + p1 * bf2f((ushort)v1[j])) +
                      (p2 * bf2f((ushort)v2[j]) + p3 * bf2f((ushort)v3[j]));
    }
    for (; i < end; i += 2) {
        int s = csr_src[i];
        float a = asrc[(size_t)s * H1 + head];
        bf16x8 v = *(const bf16x8*)(h1b + (size_t)s * HC1 + c0);
        float l = a + ad; l = l > 0.f ? l : SLOPE * l;
        float p = __expf(l);
        sump += p;
#pragma unroll
        for (int j = 0; j < 8; j++) acc[j] += p * bf2f((ushort)v[j]);
    }
    // merge the two half-waves
    sump += __shfl_xor(sump, 32);
#pragma unroll
    for (int j = 0; j < 8; j++) acc[j] += __shfl_xor(acc[j], 32);
    if (half) return;
    float inv = 1.f / sump;              // degree >= 1 (self-loop)
    float4 b0 = *(const float4*)(bias + c0);
    float4 b1 = *(const float4*)(bias + c0 + 4);
    float bb[8] = {b0.x, b0.y, b0.z, b0.w, b1.x, b1.y, b1.z, b1.w};
    uint4 uh, ul;
    uint* uhp = (uint*)&uh; uint* ulp = (uint*)&ul;
#pragma unroll
    for (int q = 0; q < 4; q++) {
        float r0 = acc[2 * q] * inv + bb[2 * q];
        float r1 = acc[2 * q + 1] * inv + bb[2 * q + 1];
        r0 = r0 > 0.f ? r0 : __expf(r0) - 1.f;     // fused ELU
        r1 = r1 > 0.f ? r1 : __expf(r1) - 1.f;
        ushort h0 = f2bf(r0), h1v = f2bf(r1);
        ushort l0 = f2bf(r0 - bf2f(h0)), l1v = f2bf(r1 - bf2f(h1v));
        uhp[q] = (uint)h0 | ((uint)h1v << 16);
        ulp[q] = (uint)l0 | ((uint)l1v << 16);
    }
    *(uint4*)(o_hi + (size_t)wid * HC1 + c0) = uh;
    *(uint4*)(o_lo + (size_t)wid * HC1 + c0) = ul;
}

// ====== layer-2 aggregation: 2 nodes/wave (half-wave/node, 2 ch/lane) ======
__global__ __launch_bounds__(256) void k_gat_aggr2(const int* __restrict__ row_off,
                                                   const int* __restrict__ csr_src,
                                                   const float* __restrict__ asrc,
                                                   const float* __restrict__ adst,
                                                   const ushort* __restrict__ h2,
                                                   const float* __restrict__ bias,
                                                   float* __restrict__ out) {
    int gw = (blockIdx.x * 256 + threadIdx.x) >> 6;    // wave id
    int lane = threadIdx.x & 63;
    int half = lane >> 5, l32 = lane & 31;
    int wid = gw * 2 + half;                           // node id (per half-wave)
    if (wid >= Nn) return;
    int c = l32 * 2;                                   // 2 channels per lane
    int beg = row_off[wid], end = row_off[wid + 1];
    float ad = adst[wid];
    float acc0 = 0.f, acc1 = 0.f, sump = 0.f;
    int i = beg;
    for (; i + 3 < end; i += 4) {
        int s0 = csr_src[i], s1 = csr_src[i + 1], s2 = csr_src[i + 2], s3 = csr_src[i + 3];
        float a0 = asrc[s0], a1 = asrc[s1], a2 = asrc[s2], a3 = asrc[s3];
        uint u0 = *(const uint*)(h2 + (size_t)s0 * S2 + c);
        uint u1 = *(const uint*)(h2 + (size_t)s1 * S2 + c);
        uint u2 = *(const uint*)(h2 + (size_t)s2 * S2 + c);
        uint u3 = *(const uint*)(h2 + (size_t)s3 * S2 + c);
        float l0 = a0 + ad; l0 = l0 > 0.f ? l0 : SLOPE * l0;
        float l1 = a1 + ad; l1 = l1 > 0.f ? l1 : SLOPE * l1;
        float l2 = a2 + ad; l2 = l2 > 0.f ? l2 : SLOPE * l2;
        float l3 = a3 + ad; l3 = l3 > 0.f ? l3 : SLOPE * l3;
        float p0 = __expf(l0), p1 = __expf(l1), p2 = __expf(l2), p3 = __expf(l3);
        sump += (p0 + p1) + (p2 + p3);
        acc0 += p0 * bf2f((ushort)(u0 & 0xffff)) + p1 * bf2f((ushort)(u1 & 0xffff)) +
                p2 * bf2f((ushort)(u2 & 0xffff)) + p3 * bf2f((ushort)(u3 & 0xffff));
        acc1 += p0 * bf2f((ushort)(u0 >> 16)) + p1 * bf2f((ushort)(u1 >> 16)) +
                p2 * bf2f((ushort)(u2 >> 16)) + p3 * bf2f((ushort)(u3 >> 16));
    }
    for (; i < end; i++) {
        int s = csr_src[i];
        float l = asrc[s] + ad;
        l = l > 0.f ? l : SLOPE * l;
        float pe = __expf(l);
        sump += pe;
        uint u = *(const uint*)(h2 + (size_t)s * S2 + c);
        acc0 += pe * bf2f((ushort)(u & 0xffff));
        acc1 += pe * bf2f((ushort)(u >> 16));
    }
    if (c < C2) {
        float inv = 1.f / sump;
        float2 r;
        r.x = acc0 * inv + bias[c];
        r.y = acc1 * inv + bias[c + 1];
        *(float2*)(out + (size_t)wid * C2 + c) = r;
    }
}

// ---------------- launch ----------------
extern "C" void kernel_launch(void* const* d_in, const int* in_sizes, int n_in,
                              void* d_out, int out_size, void* d_ws, size_t ws_size,
                              hipStream_t stream) {
    const float* x   = (const float*)d_in[0];
    const int*   ei  = (const int*)d_in[1];
    const float* w1  = (const float*)d_in[2];
    const float* as1 = (const float*)d_in[3];
    const float* ad1 = (const float*)d_in[4];
    const float* b1  = (const float*)d_in[5];
    const float* w2  = (const float*)d_in[6];
    const float* as2 = (const float*)d_in[7];
    const float* ad2 = (const float*)d_in[8];
    const float* b2  = (const float*)d_in[9];
    float* outp = (float*)d_out;

    const int* srcA = ei;
    const int* dstA = ei + Ee;

    char* W = (char*)d_ws;
    size_t o = 0;
    auto allocB = [&](size_t bytes) { void* p = W + o; o += (bytes + 255) & ~(size_t)255; return p; };

    ushort* o1hi  = (ushort*)allocB((size_t)Nn * HC1 * 2);   // 25.6 MB
    ushort* o1lo  = (ushort*)allocB((size_t)Nn * HC1 * 2);   // 25.6 MB
    ushort* wt2   = (ushort*)allocB((size_t)512 * 256 * 2);  // packed W1' (256 KB)
    ushort* wt2b  = (ushort*)allocB((size_t)512 * 48 * 2);   // packed W2' (48 KB)
    ushort* h1b   = (ushort*)allocB((size_t)Nn * HC1 * 2);   // 25.6 MB
    ushort* h2    = (ushort*)allocB((size_t)Nn * S2 * 2);    // 6.4 MB (padded)
    float*  asrc1 = (float*)allocB((size_t)Nn * H1 * 4);
    float*  adst1 = (float*)allocB((size_t)Nn * H1 * 4);
    float*  asrc2 = (float*)allocB((size_t)Nn * 4);
    float*  adst2 = (float*)allocB((size_t)Nn * 4);
    int* counts   = (int*)allocB((size_t)Nn * 4);
    int* exsc     = (int*)allocB((size_t)Nn * 4);
    int* bsum     = (int*)allocB(256 * 4);
    int* row_off  = (int*)allocB((size_t)(Nn + 1) * 4);
    int* cursor   = (int*)allocB((size_t)Nn * 4);
    int* csr_src  = (int*)allocB((size_t)ETot * 4);

    // ---- prep (weight packs + degree histogram, one dispatch) ----
    hipMemsetAsync(counts, 0, (size_t)Nn * sizeof(int), stream);
    k_prep<<<(ETot + 255) / 256, 256, 0, stream>>>(w1, wt2, w2, wt2b, dstA, counts);

    // ---- CSR build (graph shared by both layers) ----
    k_scan_block<<<NB_SCAN, 256, 0, stream>>>(counts, exsc, bsum);
    k_finalize2<<<NB_SCAN, 256, 0, stream>>>(exsc, bsum, row_off, cursor);
    k_scatter<<<(ETot + 255) / 256, 256, 0, stream>>>(srcA, dstA, cursor, csr_src);

    // ---- layer 1 (alpha fused into GEMM epilogue; x read f32-direct) ----
    k_gemm1_mfma<<<(Nn + 63) / 64, 256, 0, stream>>>(
        x, wt2, h1b, as1, ad1, asrc1, adst1, Nn);
    k_gat_aggr1<<<(int)(((size_t)Nn * 64 + 255) / 256), 256, 0, stream>>>(
        row_off, csr_src, asrc1, adst1, h1b, b1, o1hi, o1lo);

    // ---- layer 2 (alpha fused into GEMM epilogue) ----
    k_gemm2_mfma<<<(Nn + 63) / 64, 256, 0, stream>>>(
        o1hi, o1lo, wt2b, h2, as2, ad2, asrc2, adst2, Nn);
    int waves2 = (Nn + 1) / 2;
    k_gat_aggr2<<<(int)(((size_t)waves2 * 64 + 255) / 256), 256, 0, stream>>>(
        row_off, csr_src, asrc2, adst2, h2, b2, outp);
}

// Round 13
// 234.485 us; speedup vs baseline: 1.2867x; 1.1318x over previous
//
#include <hip/hip_runtime.h>
#include <cstdint>
#include <cstddef>

// ---------------- problem constants (from setup_inputs) ----------------
constexpr int Nn   = 50000;            // nodes
constexpr int Ee   = 800000;           // edges (without self loops)
constexpr int ETot = Ee + Nn;          // 850000 with self loops
constexpr int H1   = 8;                // heads layer 1
constexpr int C1h  = 32;               // channels/head layer 1
constexpr int HC1  = 256;              // H1*C1h
constexpr int C2   = 40;               // classes (layer 2, 1 head)
constexpr int S2   = 64;               // padded h2 row stride (halfs) = 128 B
constexpr float SLOPE = 0.2f;          // leaky_relu negative slope
constexpr int NB_SCAN = (Nn + 255) / 256;   // 196 scan blocks

typedef _Float16 f16x8 __attribute__((ext_vector_type(8)));  // 8 fp16 (4 VGPRs)
typedef __attribute__((ext_vector_type(4))) float f32x4;     // MFMA accumulator

__device__ __forceinline__ ushort f2h(float f) {             // RNE f32->fp16
    _Float16 h = (_Float16)f;
    ushort u; __builtin_memcpy(&u, &h, 2);
    return u;
}
__device__ __forceinline__ float h2f(ushort u) {
    _Float16 h; __builtin_memcpy(&h, &u, 2);
    return (float)h;
}

// async global->LDS, 16 B per lane; LDS dest = wave-uniform base + lane*16
__device__ __forceinline__ void gload16(const void* g, void* lds) {
    typedef const __attribute__((address_space(1))) unsigned int GU;
    typedef __attribute__((address_space(3))) unsigned int LU;
    __builtin_amdgcn_global_load_lds((GU*)g, (LU*)lds, 16, 0, 0);
}

// ====== merged prep: W1 pack fp16 | W2 pack fp16 | dst hist =====
// W1 -> WT2[((kb)*256+col)*8 + kr], kb in [0,32).  W2 likewise with 48 cols.
__global__ void k_prep(const float* __restrict__ w1, ushort* __restrict__ WT2,
                       const float* __restrict__ w2, ushort* __restrict__ WT2b,
                       const int* __restrict__ dstA, int* __restrict__ counts) {
    int t = blockIdx.x * blockDim.x + threadIdx.x;
    if (t < ETot) {
        int d = (t < Ee) ? dstA[t] : t - Ee;
        atomicAdd(&counts[d], 1);
    }
    if (t < 256 * 256) {
        int k = t >> 8, col = t & 255;
        float w = w1[(size_t)k * 256 + col];
        int kb = k >> 3, kr = k & 7;
        WT2[((size_t)kb * 256 + col) * 8 + kr] = f2h(w);
    }
    if (t < 256 * 48) {
        int k = t / 48, col = t % 48;
        float w = (col < C2) ? w2[(size_t)k * C2 + col] : 0.f;
        int kb = k >> 3, kr = k & 7;
        WT2b[((size_t)kb * 48 + col) * 8 + kr] = f2h(w);
    }
}

// ================= CSR build (scan -> merged top+finalize -> scatter) ========
__global__ __launch_bounds__(256) void k_scan_block(const int* __restrict__ counts,
                                                    int* __restrict__ exsc,
                                                    int* __restrict__ bsum) {
    __shared__ int sm[256];
    int i = blockIdx.x * 256 + threadIdx.x;
    int v = (i < Nn) ? counts[i] : 0;
    sm[threadIdx.x] = v;
    __syncthreads();
#pragma unroll
    for (int off = 1; off < 256; off <<= 1) {
        int t = (threadIdx.x >= off) ? sm[threadIdx.x - off] : 0;
        __syncthreads();
        sm[threadIdx.x] += t;
        __syncthreads();
    }
    if (i < Nn) exsc[i] = sm[threadIdx.x] - v;
    if (threadIdx.x == 255) bsum[blockIdx.x] = sm[255];
}

__global__ __launch_bounds__(256) void k_finalize2(const int* __restrict__ exsc,
                                                   const int* __restrict__ bsum,
                                                   int* __restrict__ row_off,
                                                   int* __restrict__ cursor) {
    __shared__ int sm[256];
    int t = threadIdx.x;
    int v = (t < NB_SCAN) ? bsum[t] : 0;
    sm[t] = v;
    __syncthreads();
#pragma unroll
    for (int off = 1; off < 256; off <<= 1) {
        int x = (t >= off) ? sm[t - off] : 0;
        __syncthreads();
        sm[t] += x;
        __syncthreads();
    }
    int i = blockIdx.x * 256 + t;
    if (i < Nn) {
        int r = exsc[i] + sm[blockIdx.x] - bsum[blockIdx.x];  // exclusive boff
        row_off[i] = r;
        cursor[i] = r;
    }
    if (i == 0) row_off[Nn] = ETot;
}

__global__ void k_scatter(const int* __restrict__ srcA, const int* __restrict__ dstA,
                          int* __restrict__ cursor, int* __restrict__ csr_src) {
    int e = blockIdx.x * blockDim.x + threadIdx.x;
    if (e >= ETot) return;
    int s, d;
    if (e < Ee) { s = srcA[e]; d = dstA[e]; } else { s = e - Ee; d = s; }
    int pos = atomicAdd(&cursor[d], 1);
    csr_src[pos] = s;
}

// ========== GEMM1 (MFMA fp16, single term): [M,256]x[256,256] ============
// 64x256 tile, 4 waves (wave w = col block, acc[4][4]).  A: reg-stage f32 ->
// convert fp16 -> LDS dbuf; 8 K-steps, 16 MFMA/wave/step.  B fragments direct
// from L2-resident packed WT2 (131 KB).  Fused alpha epilogue.
__global__ __launch_bounds__(256, 3) void k_gemm1_mfma(const float* __restrict__ x,
                                                       const ushort* __restrict__ WT2,
                                                       ushort* __restrict__ h1b,
                                                       const float* __restrict__ a_s,
                                                       const float* __restrict__ a_d,
                                                       float* __restrict__ asrc1,
                                                       float* __restrict__ adst1, int M) {
    __shared__ __align__(16) ushort As[2][64 * 32];    // 4 KB each: (kc*64+row)*8
    const int tid = threadIdx.x;
    const int bm = blockIdx.x * 64;
    const int lane = tid & 63;
    const int w = tid >> 6;                            // wave = col block
    const int l16 = lane & 15, lk = lane >> 4;

    const int sakc = tid >> 6, sarow = tid & 63;       // stage slot (kc, row)
    int arow = bm + sarow; arow = arow < M ? arow : M - 1;
    const float* aptr = x + (size_t)arow * 256 + sakc * 8;
    const int sidx = (sakc * 64 + sarow) * 8;          // LDS dest (halfs)

    float4 f0, f1;
    auto loadA = [&](int t) {
        f0 = *(const float4*)(aptr + t * 32);
        f1 = *(const float4*)(aptr + t * 32 + 4);
    };
    auto cvtWrite = [&](int buf) {
        float ff[8] = {f0.x, f0.y, f0.z, f0.w, f1.x, f1.y, f1.z, f1.w};
        ushort hh[8];
#pragma unroll
        for (int j = 0; j < 8; j++) hh[j] = f2h(ff[j]);
        *(uint4*)(As[buf] + sidx) = *(uint4*)hh;
    };

    f32x4 acc[4][4] = {};
    loadA(0);
    cvtWrite(0);
    __syncthreads();
    for (int t = 0; t < 8; t++) {
        int buf = t & 1;
        if (t + 1 < 8) loadA(t + 1);          // loads in flight over MFMA
        f16x8 a[4];
#pragma unroll
        for (int m = 0; m < 4; m++)
            a[m] = *(const f16x8*)(As[buf] + (lk * 64 + m * 16 + l16) * 8);
        f16x8 b[4];
#pragma unroll
        for (int n = 0; n < 4; n++)
            b[n] = *(const f16x8*)(WT2 +
                ((size_t)(t * 4 + lk) * 256 + w * 64 + n * 16 + l16) * 8);
#pragma unroll
        for (int m = 0; m < 4; m++)
#pragma unroll
            for (int n = 0; n < 4; n++)
                acc[m][n] = __builtin_amdgcn_mfma_f32_16x16x32_f16(a[m], b[n], acc[m][n], 0, 0, 0);
        if (t + 1 < 8) cvtWrite((t + 1) & 1); // write next buf (safe: dbuf)
        __syncthreads();
    }
    // ---- epilogue: h1b (fp16) store + fused alpha (heads 2w, 2w+1) ----
    float as_v[4], ad_v[4];
#pragma unroll
    for (int n = 0; n < 4; n++) {
        int col = w * 64 + n * 16 + l16;
        as_v[n] = a_s[col];
        ad_v[n] = a_d[col];
    }
#pragma unroll
    for (int m = 0; m < 4; m++) {
#pragma unroll
        for (int j = 0; j < 4; j++) {
            int row = bm + m * 16 + lk * 4 + j;
            float ps0 = acc[m][0][j] * as_v[0] + acc[m][1][j] * as_v[1];
            float ps1 = acc[m][2][j] * as_v[2] + acc[m][3][j] * as_v[3];
            float pd0 = acc[m][0][j] * ad_v[0] + acc[m][1][j] * ad_v[1];
            float pd1 = acc[m][2][j] * ad_v[2] + acc[m][3][j] * ad_v[3];
#pragma unroll
            for (int off = 1; off < 16; off <<= 1) {
                ps0 += __shfl_xor(ps0, off);
                ps1 += __shfl_xor(ps1, off);
                pd0 += __shfl_xor(pd0, off);
                pd1 += __shfl_xor(pd1, off);
            }
            if (row < M) {
#pragma unroll
                for (int n = 0; n < 4; n++)
                    h1b[(size_t)row * 256 + w * 64 + n * 16 + l16] = f2h(acc[m][n][j]);
                if (l16 == 0) {
                    asrc1[(size_t)row * H1 + w * 2]     = ps0;
                    asrc1[(size_t)row * H1 + w * 2 + 1] = ps1;
                    adst1[(size_t)row * H1 + w * 2]     = pd0;
                    adst1[(size_t)row * H1 + w * 2 + 1] = pd1;
                }
            }
        }
    }
}

// ========== GEMM2 (MFMA fp16, single term): [M,256]x[256,48] ==========
// 64-row tile, 4 waves x 16 rows (acc[3]); A = out1 (fp16) via gload16 dbuf,
// 8 K-steps; B2 (24 KB) direct from L2.  Fused alpha2 epilogue.
__global__ __launch_bounds__(256, 4) void k_gemm2_mfma(const ushort* __restrict__ o1,
                                                       const ushort* __restrict__ WT,
                                                       ushort* __restrict__ h2,
                                                       const float* __restrict__ a_s,
                                                       const float* __restrict__ a_d,
                                                       float* __restrict__ asrc2,
                                                       float* __restrict__ adst2, int M) {
    __shared__ __align__(16) ushort As[2][64 * 32];
    const int tid = threadIdx.x;
    const int bm = blockIdx.x * 64;
    const int lane = tid & 63;
    const int w = tid >> 6;
    const int l16 = lane & 15, lk = lane >> 4;

    const int sakc = tid >> 6, sarow = tid & 63;
    int arow = bm + sarow; arow = arow < M ? arow : M - 1;

    auto stageA = [&](int buf, int t) {
        gload16(o1 + (size_t)arow * 256 + t * 32 + sakc * 8, As[buf] + tid * 8);
    };

    f32x4 acc[3] = {};
    stageA(0, 0);
    __syncthreads();
    int buf = 0;
    for (int t = 0; t < 8; t++) {
        if (t + 1 < 8) stageA(buf ^ 1, t + 1);
        f16x8 a2 = *(const f16x8*)(As[buf] + (lk * 64 + w * 16 + l16) * 8);
        f16x8 b2[3];
#pragma unroll
        for (int n = 0; n < 3; n++)
            b2[n] = *(const f16x8*)(WT +
                ((size_t)(t * 4 + lk) * 48 + n * 16 + l16) * 8);
#pragma unroll
        for (int n = 0; n < 3; n++)
            acc[n] = __builtin_amdgcn_mfma_f32_16x16x32_f16(a2, b2[n], acc[n], 0, 0, 0);
        __syncthreads();
        buf ^= 1;
    }
    // ---- epilogue: h2 (fp16, padded stride) + fused alpha2 ----
    float asv[3], adv[3];
#pragma unroll
    for (int n = 0; n < 3; n++) {
        int col = n * 16 + l16;
        asv[n] = (col < C2) ? a_s[col] : 0.f;
        adv[n] = (col < C2) ? a_d[col] : 0.f;
    }
#pragma unroll
    for (int j = 0; j < 4; j++) {
        int row = bm + w * 16 + lk * 4 + j;
        float ps = acc[0][j] * asv[0] + acc[1][j] * asv[1] + acc[2][j] * asv[2];
        float pd = acc[0][j] * adv[0] + acc[1][j] * adv[1] + acc[2][j] * adv[2];
#pragma unroll
        for (int off = 1; off < 16; off <<= 1) {
            ps += __shfl_xor(ps, off);
            pd += __shfl_xor(pd, off);
        }
        if (row < M) {
#pragma unroll
            for (int n = 0; n < 3; n++)
                h2[(size_t)row * S2 + n * 16 + l16] = f2h(acc[n][j]);
            if (l16 == 0) { asrc2[row] = ps; adst2[row] = pd; }
        }
    }
}

// ======== layer-1 aggregation: half-wave per edge, 4-deep unrolled ========
// Gathers fp16 h1b rows; epilogue writes out1 as single fp16.
__global__ __launch_bounds__(256) void k_gat_aggr1(const int* __restrict__ row_off,
                                                   const int* __restrict__ csr_src,
                                                   const float* __restrict__ asrc,
                                                   const float* __restrict__ adst,
                                                   const ushort* __restrict__ h1b,
                                                   const float* __restrict__ bias,
                                                   ushort* __restrict__ o1) {
    int wid = (blockIdx.x * 256 + threadIdx.x) >> 6;   // node id
    if (wid >= Nn) return;
    int lane = threadIdx.x & 63;
    int half = lane >> 5, l32 = lane & 31;
    int head = l32 >> 2;                 // 4 lanes per head, 8 ch each
    int c0 = l32 * 8;
    int beg = row_off[wid], end = row_off[wid + 1];
    float ad = adst[(size_t)wid * H1 + head];
    float acc[8] = {};
    float sump = 0.f;
    int i = beg + half;
    for (; i + 6 < end; i += 8) {        // 4 edges per half per iter
        int s0 = csr_src[i],     s1 = csr_src[i + 2];
        int s2 = csr_src[i + 4], s3 = csr_src[i + 6];
        float a0 = asrc[(size_t)s0 * H1 + head], a1 = asrc[(size_t)s1 * H1 + head];
        float a2 = asrc[(size_t)s2 * H1 + head], a3 = asrc[(size_t)s3 * H1 + head];
        ushort4 w0 = *(const ushort4*)(h1b + (size_t)s0 * HC1 + c0);
        ushort4 w0b = *(const ushort4*)(h1b + (size_t)s0 * HC1 + c0 + 4);
        ushort4 w1 = *(const ushort4*)(h1b + (size_t)s1 * HC1 + c0);
        ushort4 w1b = *(const ushort4*)(h1b + (size_t)s1 * HC1 + c0 + 4);
        ushort4 w2 = *(const ushort4*)(h1b + (size_t)s2 * HC1 + c0);
        ushort4 w2b = *(const ushort4*)(h1b + (size_t)s2 * HC1 + c0 + 4);
        ushort4 w3 = *(const ushort4*)(h1b + (size_t)s3 * HC1 + c0);
        ushort4 w3b = *(const ushort4*)(h1b + (size_t)s3 * HC1 + c0 + 4);
        float l0 = a0 + ad; l0 = l0 > 0.f ? l0 : SLOPE * l0;
        float l1 = a1 + ad; l1 = l1 > 0.f ? l1 : SLOPE * l1;
        float l2 = a2 + ad; l2 = l2 > 0.f ? l2 : SLOPE * l2;
        float l3 = a3 + ad; l3 = l3 > 0.f ? l3 : SLOPE * l3;
        float p0 = __expf(l0), p1 = __expf(l1), p2 = __expf(l2), p3 = __expf(l3);
        sump += (p0 + p1) + (p2 + p3);
        ushort v0[8] = {w0.x, w0.y, w0.z, w0.w, w0b.x, w0b.y, w0b.z, w0b.w};
        ushort v1[8] = {w1.x, w1.y, w1.z, w1.w, w1b.x, w1b.y, w1b.z, w1b.w};
        ushort v2[8] = {w2.x, w2.y, w2.z, w2.w, w2b.x, w2b.y, w2b.z, w2b.w};
        ushort v3[8] = {w3.x, w3.y, w3.z, w3.w, w3b.x, w3b.y, w3b.z, w3b.w};
#pragma unroll
        for (int j = 0; j < 8; j++)
            acc[j] += (p0 * h2f(v0[j]) + p1 * h2f(v1[j])) +
                      (p2 * h2f(v2[j]) + p3 * h2f(v3[j]));
    }
    for (; i < end; i += 2) {
        int s = csr_src[i];
        float a = asrc[(size_t)s * H1 + head];
        ushort4 wv = *(const ushort4*)(h1b + (size_t)s * HC1 + c0);
        ushort4 wb = *(const ushort4*)(h1b + (size_t)s * HC1 + c0 + 4);
        float l = a + ad; l = l > 0.f ? l : SLOPE * l;
        float p = __expf(l);
        sump += p;
        ushort v[8] = {wv.x, wv.y, wv.z, wv.w, wb.x, wb.y, wb.z, wb.w};
#pragma unroll
        for (int j = 0; j < 8; j++) acc[j] += p * h2f(v[j]);
    }
    // merge the two half-waves
    sump += __shfl_xor(sump, 32);
#pragma unroll
    for (int j = 0; j < 8; j++) acc[j] += __shfl_xor(acc[j], 32);
    if (half) return;
    float inv = 1.f / sump;              // degree >= 1 (self-loop)
    float4 b0 = *(const float4*)(bias + c0);
    float4 b1 = *(const float4*)(bias + c0 + 4);
    float bb[8] = {b0.x, b0.y, b0.z, b0.w, b1.x, b1.y, b1.z, b1.w};
    ushort hh[8];
#pragma unroll
    for (int j = 0; j < 8; j++) {
        float r = acc[j] * inv + bb[j];
        r = r > 0.f ? r : __expf(r) - 1.f;         // fused ELU
        hh[j] = f2h(r);
    }
    *(uint4*)(o1 + (size_t)wid * HC1 + c0) = *(uint4*)hh;
}

// ====== layer-2 aggregation: 2 nodes/wave (half-wave/node, 2 ch/lane) ======
__global__ __launch_bounds__(256) void k_gat_aggr2(const int* __restrict__ row_off,
                                                   const int* __restrict__ csr_src,
                                                   const float* __restrict__ asrc,
                                                   const float* __restrict__ adst,
                                                   const ushort* __restrict__ h2,
                                                   const float* __restrict__ bias,
                                                   float* __restrict__ out) {
    int gw = (blockIdx.x * 256 + threadIdx.x) >> 6;    // wave id
    int lane = threadIdx.x & 63;
    int half = lane >> 5, l32 = lane & 31;
    int wid = gw * 2 + half;                           // node id (per half-wave)
    if (wid >= Nn) return;
    int c = l32 * 2;                                   // 2 channels per lane
    int beg = row_off[wid], end = row_off[wid + 1];
    float ad = adst[wid];
    float acc0 = 0.f, acc1 = 0.f, sump = 0.f;
    int i = beg;
    for (; i + 3 < end; i += 4) {
        int s0 = csr_src[i], s1 = csr_src[i + 1], s2 = csr_src[i + 2], s3 = csr_src[i + 3];
        float a0 = asrc[s0], a1 = asrc[s1], a2 = asrc[s2], a3 = asrc[s3];
        uint u0 = *(const uint*)(h2 + (size_t)s0 * S2 + c);
        uint u1 = *(const uint*)(h2 + (size_t)s1 * S2 + c);
        uint u2 = *(const uint*)(h2 + (size_t)s2 * S2 + c);
        uint u3 = *(const uint*)(h2 + (size_t)s3 * S2 + c);
        float l0 = a0 + ad; l0 = l0 > 0.f ? l0 : SLOPE * l0;
        float l1 = a1 + ad; l1 = l1 > 0.f ? l1 : SLOPE * l1;
        float l2 = a2 + ad; l2 = l2 > 0.f ? l2 : SLOPE * l2;
        float l3 = a3 + ad; l3 = l3 > 0.f ? l3 : SLOPE * l3;
        float p0 = __expf(l0), p1 = __expf(l1), p2 = __expf(l2), p3 = __expf(l3);
        sump += (p0 + p1) + (p2 + p3);
        acc0 += p0 * h2f((ushort)(u0 & 0xffff)) + p1 * h2f((ushort)(u1 & 0xffff)) +
                p2 * h2f((ushort)(u2 & 0xffff)) + p3 * h2f((ushort)(u3 & 0xffff));
        acc1 += p0 * h2f((ushort)(u0 >> 16)) + p1 * h2f((ushort)(u1 >> 16)) +
                p2 * h2f((ushort)(u2 >> 16)) + p3 * h2f((ushort)(u3 >> 16));
    }
    for (; i < end; i++) {
        int s = csr_src[i];
        float l = asrc[s] + ad;
        l = l > 0.f ? l : SLOPE * l;
        float pe = __expf(l);
        sump += pe;
        uint u = *(const uint*)(h2 + (size_t)s * S2 + c);
        acc0 += pe * h2f((ushort)(u & 0xffff));
        acc1 += pe * h2f((ushort)(u >> 16));
    }
    if (c < C2) {
        float inv = 1.f / sump;
        float2 r;
        r.x = acc0 * inv + bias[c];
        r.y = acc1 * inv + bias[c + 1];
        *(float2*)(out + (size_t)wid * C2 + c) = r;
    }
}

// ---------------- launch ----------------
extern "C" void kernel_launch(void* const* d_in, const int* in_sizes, int n_in,
                              void* d_out, int out_size, void* d_ws, size_t ws_size,
                              hipStream_t stream) {
    const float* x   = (const float*)d_in[0];
    const int*   ei  = (const int*)d_in[1];
    const float* w1  = (const float*)d_in[2];
    const float* as1 = (const float*)d_in[3];
    const float* ad1 = (const float*)d_in[4];
    const float* b1  = (const float*)d_in[5];
    const float* w2  = (const float*)d_in[6];
    const float* as2 = (const float*)d_in[7];
    const float* ad2 = (const float*)d_in[8];
    const float* b2  = (const float*)d_in[9];
    float* outp = (float*)d_out;

    const int* srcA = ei;
    const int* dstA = ei + Ee;

    char* W = (char*)d_ws;
    size_t o = 0;
    auto allocB = [&](size_t bytes) { void* p = W + o; o += (bytes + 255) & ~(size_t)255; return p; };

    ushort* o1    = (ushort*)allocB((size_t)Nn * HC1 * 2);   // 25.6 MB (fp16 out1)
    ushort* wt2   = (ushort*)allocB((size_t)256 * 256 * 2);  // packed W1 fp16 (131 KB)
    ushort* wt2b  = (ushort*)allocB((size_t)256 * 48 * 2);   // packed W2 fp16 (24 KB)
    ushort* h1b   = (ushort*)allocB((size_t)Nn * HC1 * 2);   // 25.6 MB (fp16)
    ushort* h2    = (ushort*)allocB((size_t)Nn * S2 * 2);    // 6.4 MB (fp16, padded)
    float*  asrc1 = (float*)allocB((size_t)Nn * H1 * 4);
    float*  adst1 = (float*)allocB((size_t)Nn * H1 * 4);
    float*  asrc2 = (float*)allocB((size_t)Nn * 4);
    float*  adst2 = (float*)allocB((size_t)Nn * 4);
    int* counts   = (int*)allocB((size_t)Nn * 4);
    int* exsc     = (int*)allocB((size_t)Nn * 4);
    int* bsum     = (int*)allocB(256 * 4);
    int* row_off  = (int*)allocB((size_t)(Nn + 1) * 4);
    int* cursor   = (int*)allocB((size_t)Nn * 4);
    int* csr_src  = (int*)allocB((size_t)ETot * 4);

    // ---- prep (weight packs + degree histogram, one dispatch) ----
    hipMemsetAsync(counts, 0, (size_t)Nn * sizeof(int), stream);
    k_prep<<<(ETot + 255) / 256, 256, 0, stream>>>(w1, wt2, w2, wt2b, dstA, counts);

    // ---- CSR build (graph shared by both layers) ----
    k_scan_block<<<NB_SCAN, 256, 0, stream>>>(counts, exsc, bsum);
    k_finalize2<<<NB_SCAN, 256, 0, stream>>>(exsc, bsum, row_off, cursor);
    k_scatter<<<(ETot + 255) / 256, 256, 0, stream>>>(srcA, dstA, cursor, csr_src);

    // ---- layer 1 (alpha fused into GEMM epilogue; x read f32-direct) ----
    k_gemm1_mfma<<<(Nn + 63) / 64, 256, 0, stream>>>(
        x, wt2, h1b, as1, ad1, asrc1, adst1, Nn);
    k_gat_aggr1<<<(int)(((size_t)Nn * 64 + 255) / 256), 256, 0, stream>>>(
        row_off, csr_src, asrc1, adst1, h1b, b1, o1);

    // ---- layer 2 (alpha fused into GEMM epilogue) ----
    k_gemm2_mfma<<<(Nn + 63) / 64, 256, 0, stream>>>(
        o1, wt2b, h2, as2, ad2, asrc2, adst2, Nn);
    int waves2 = (Nn + 1) / 2;
    k_gat_aggr2<<<(int)(((size_t)waves2 * 64 + 255) / 256), 256, 0, stream>>>(
        row_off, csr_src, asrc2, adst2, h2, b2, outp);
}